// Round 6
// baseline (178.970 us; speedup 1.0000x reference)
//
#include <hip/hip_runtime.h>

#define NTOK 4096
#define DIM 32
#define NBH 32              // B*H
#define NPAIR2 528          // upper triangle incl. diagonal of 32x32
#define NROWS 560           // + 32 kv1 rows
#define BHF (NROWS * 32 + 64)       // floats per bh: rows + ksum(32) + vsum(32) = 17984
#define SLOT (NBH * BHF)            // 575488 floats per slot (2.30 MB)
#define TILE 64
#define LSTR 36             // padded LDS row stride; col 32 = 1.0 (kv1), col 34 = 0.0 (dummy)
#define P1T 320             // phase1 threads (5 waves); rows: t and t+320

__device__ __forceinline__ int tri_start(int d) { return (d * (65 - d)) >> 1; }

__device__ __forceinline__ int tri_decode_d(int p) {
    int d = (int)((65.0f - sqrtf((float)(4225 - 8 * p))) * 0.5f);
    if (d < 0) d = 0;
    if (d > 31) d = 31;
    while (d < 31 && tri_start(d + 1) <= p) ++d;
    while (d > 0 && tri_start(d) > p) --d;
    return d;
}

__device__ __forceinline__ void row_operands(int row, int& ia, int& ib) {
    if (row < NPAIR2) {
        const int d = tri_decode_d(row);
        ia = d; ib = d + (row - tri_start(d));
    } else if (row < NROWS) {
        ia = row - NPAIR2; ib = 32;      // kv1 row: s = k_d * 1.0 (pad col 32)
    } else {
        ia = 34; ib = 34;                // dummy row: s = 0 * 0 (pad col 34)
    }
}

// Phase 1: grid (chunk, bh), 320 threads. Thread t owns rows {t, t+320}, full f.
// k staged in LDS (per-lane gather); v read via wave-uniform GLOBAL loads -> SGPRs,
// consumed as the scalar operand of v_fmac. Wave 4 lanes also accumulate ksum/vsum.
__global__ __launch_bounds__(P1T) void phase1_kernel(const float* __restrict__ qkv,
                                                     float* __restrict__ ws, int direct) {
    const int chunk = blockIdx.x;
    const int bh = blockIdx.y;
    const int CHt = NTOK / gridDim.x;
    const int t = threadIdx.x;
    const float* kptr = qkv + (size_t)(NBH + bh) * (NTOK * DIM);
    const float* vptr = qkv + (size_t)(2 * NBH + bh) * (NTOK * DIM);
    float* base = ws + (direct ? (size_t)0 : (size_t)SLOT * (1 + chunk)) + (size_t)bh * BHF;

    __shared__ __align__(16) float sk[TILE][LSTR];
    __shared__ __align__(16) float sv[TILE][LSTR];

    int ia0, ib0, ia1, ib1;
    row_operands(t, ia0, ib0);
    row_operands(t + P1T, ia1, ib1);
    const float* a0 = &sk[0][ia0];
    const float* b0 = &sk[0][ib0];
    const float* a1 = &sk[0][ia1];
    const float* b1 = &sk[0][ib1];
    // wave-4 running sums: lanes 256..287 -> ksum col, 288..319 -> vsum col
    const float* sums = (t >= 288) ? &sv[0][t - 288] : ((t >= 256) ? &sk[0][t - 256] : &sk[0][0]);

    float acc0[32], acc1[32];
#pragma unroll
    for (int f = 0; f < 32; ++f) { acc0[f] = 0.f; acc1[f] = 0.f; }
    float accs = 0.f;

    // pad columns (staging only writes cols 0..31; first barrier publishes)
    if (t < 64) sk[t][32] = 1.0f;
    else if (t < 128) sk[t - 64][34] = 0.0f;

    const int n0 = chunk * CHt;
    for (int nt = 0; nt < CHt; nt += TILE) {
        __syncthreads();
        if (t < 256) {   // wave-uniform: wave 4 skips staging
            const float4* kg4 = (const float4*)(kptr + (size_t)(n0 + nt) * DIM);
            const float4* vg4 = (const float4*)(vptr + (size_t)(n0 + nt) * DIM);
            const int i0 = t, i1 = t + 256;
            *(float4*)&sk[i0 >> 3][(i0 & 7) << 2] = kg4[i0];
            *(float4*)&sk[i1 >> 3][(i1 & 7) << 2] = kg4[i1];
            *(float4*)&sv[i0 >> 3][(i0 & 7) << 2] = vg4[i0];
            *(float4*)&sv[i1 >> 3][(i1 & 7) << 2] = vg4[i1];
        }
        __syncthreads();
#pragma unroll 2
        for (int nn = 0; nn < TILE; ++nn) {
            // per-lane k gather from LDS (broadcast-heavy, <=2-way bank alias)
            const float s0 = a0[nn * LSTR] * b0[nn * LSTR];
            const float s1 = a1[nn * LSTR] * b1[nn * LSTR];
            // wave-uniform v row from GLOBAL -> scalar loads -> SGPR operands
            const float* vrow = vptr + (size_t)(n0 + nt + nn) * DIM;
            float4 w[8];
#pragma unroll
            for (int j = 0; j < 8; ++j) w[j] = ((const float4*)vrow)[j];
#pragma unroll
            for (int j = 0; j < 8; ++j) {
                acc0[4 * j + 0] += s0 * w[j].x; acc0[4 * j + 1] += s0 * w[j].y;
                acc0[4 * j + 2] += s0 * w[j].z; acc0[4 * j + 3] += s0 * w[j].w;
                acc1[4 * j + 0] += s1 * w[j].x; acc1[4 * j + 1] += s1 * w[j].y;
                acc1[4 * j + 2] += s1 * w[j].z; acc1[4 * j + 3] += s1 * w[j].w;
            }
            if (t >= 256) accs += sums[nn * LSTR];   // wave-uniform branch
        }
    }

    // flush rows (row0 = t always real; row1 real iff t < 240)
    {
        float* dst = base + (size_t)t * 32;
#pragma unroll
        for (int j = 0; j < 8; ++j) {
            float4 v; v.x = acc0[4 * j]; v.y = acc0[4 * j + 1];
            v.z = acc0[4 * j + 2]; v.w = acc0[4 * j + 3];
            ((float4*)dst)[j] = v;
        }
    }
    if (t < 240) {
        float* dst = base + (size_t)(t + P1T) * 32;
#pragma unroll
        for (int j = 0; j < 8; ++j) {
            float4 v; v.x = acc1[4 * j]; v.y = acc1[4 * j + 1];
            v.z = acc1[4 * j + 2]; v.w = acc1[4 * j + 3];
            ((float4*)dst)[j] = v;
        }
    }
    if (t >= 256) base[NROWS * 32 + (t - 256)] = accs;   // ksum (0..31), vsum (32..63)
}

// Sum partial slots 1..nch into slot 0.
__global__ __launch_bounds__(256) void reduce_kernel(float* __restrict__ ws, int nch) {
    const int i = blockIdx.x * 256 + threadIdx.x;
    if (i >= SLOT / 4) return;
    float4 a = {0.f, 0.f, 0.f, 0.f};
    for (int c = 1; c <= nch; ++c) {
        const float4 p = ((const float4*)(ws + (size_t)SLOT * c))[i];
        a.x += p.x; a.y += p.y; a.z += p.z; a.w += p.w;
    }
    ((float4*)ws)[i] = a;
}

// Phase 2: 512 tokens per block (thread t owns tokens t and t+256), 16 of 32 f per
// block (blockIdx.z). Per row: 32 fmac + 2 smul of VALU per 1 row-load -> the
// unroll-4 window (~280 cy VALU, 16 s_loads = 64 SGPRs in flight) covers L2 latency.
__global__ __launch_bounds__(256) void phase2_kernel(const float* __restrict__ qkv,
                                                     const float* __restrict__ ws,
                                                     float* __restrict__ out) {
    const int bh = blockIdx.y;
    const int f0 = blockIdx.z << 4;
    const int t = threadIdx.x;
    const int tok0 = blockIdx.x * 512;
    const float* qptr = qkv + (size_t)bh * (NTOK * DIM) + (size_t)tok0 * DIM;
    const float* base = ws + (size_t)bh * BHF;
    const float* ksum = base + NROWS * 32;
    const float* vsum = ksum + 32;

    __shared__ float qT[32][512];
    {
#pragma unroll
        for (int half = 0; half < 2; ++half) {
            const int tok = t + half * 256;
            const float4* q4 = (const float4*)qptr + (size_t)tok * 8;
#pragma unroll
            for (int i = 0; i < 8; ++i) {
                const float4 v = q4[i];
                qT[4 * i + 0][tok] = v.x; qT[4 * i + 1][tok] = v.y;
                qT[4 * i + 2][tok] = v.z; qT[4 * i + 3][tok] = v.w;
            }
        }
    }
    __syncthreads();

    const int ta = t;
    const int tb = t + 256;
    float ya[16], yb[16];
#pragma unroll
    for (int j = 0; j < 4; ++j) {
        const float4 v = *(const float4*)(vsum + f0 + 4 * j);
        ya[4 * j + 0] = v.x; ya[4 * j + 1] = v.y; ya[4 * j + 2] = v.z; ya[4 * j + 3] = v.w;
        yb[4 * j + 0] = v.x; yb[4 * j + 1] = v.y; yb[4 * j + 2] = v.z; yb[4 * j + 3] = v.w;
    }
    float qka = 0.f, qkb = 0.f;

    const float* rowp = base + f0;   // walks the 528 triangle rows, then 32 kv1 rows
#pragma unroll 1
    for (int d = 0; d < 32; ++d) {
        const float qda = qT[d][ta];
        const float qdb = qT[d][tb];
        const float ks = ksum[d];
        qka += qda * ks;
        qkb += qdb * ks;
        {   // diagonal row (e == d): s = 0.5 qd^2
            const float sa = 0.5f * qda * qda;
            const float sb = 0.5f * qdb * qdb;
            const float4* r = (const float4*)rowp;
#pragma unroll
            for (int j = 0; j < 4; ++j) {
                const float4 w = r[j];
                ya[4 * j + 0] += sa * w.x; ya[4 * j + 1] += sa * w.y;
                ya[4 * j + 2] += sa * w.z; ya[4 * j + 3] += sa * w.w;
                yb[4 * j + 0] += sb * w.x; yb[4 * j + 1] += sb * w.y;
                yb[4 * j + 2] += sb * w.z; yb[4 * j + 3] += sb * w.w;
            }
            rowp += 32;
        }
#pragma unroll 4
        for (int e = d + 1; e < 32; ++e) {
            const float sa = qda * qT[e][ta];
            const float sb = qdb * qT[e][tb];
            const float4* r = (const float4*)rowp;
#pragma unroll
            for (int j = 0; j < 4; ++j) {
                const float4 w = r[j];
                ya[4 * j + 0] += sa * w.x; ya[4 * j + 1] += sa * w.y;
                ya[4 * j + 2] += sa * w.z; ya[4 * j + 3] += sa * w.w;
                yb[4 * j + 0] += sb * w.x; yb[4 * j + 1] += sb * w.y;
                yb[4 * j + 2] += sb * w.z; yb[4 * j + 3] += sb * w.w;
            }
            rowp += 32;
        }
    }
    // kv1 rows
#pragma unroll 4
    for (int d = 0; d < 32; ++d) {
        const float qda = qT[d][ta];
        const float qdb = qT[d][tb];
        const float4* r = (const float4*)rowp;
#pragma unroll
        for (int j = 0; j < 4; ++j) {
            const float4 w = r[j];
            ya[4 * j + 0] += qda * w.x; ya[4 * j + 1] += qda * w.y;
            ya[4 * j + 2] += qda * w.z; ya[4 * j + 3] += qda * w.w;
            yb[4 * j + 0] += qdb * w.x; yb[4 * j + 1] += qdb * w.y;
            yb[4 * j + 2] += qdb * w.z; yb[4 * j + 3] += qdb * w.w;
        }
        rowp += 32;
    }

    const float inva = 1.0f / (0.5f * qka * qka + qka + 1.0f);
    const float invb = 1.0f / (0.5f * qkb * qkb + qkb + 1.0f);
    float4* oa = (float4*)(out + (size_t)bh * (NTOK * DIM) + (size_t)(tok0 + ta) * DIM + f0);
    float4* ob = (float4*)(out + (size_t)bh * (NTOK * DIM) + (size_t)(tok0 + tb) * DIM + f0);
#pragma unroll
    for (int j = 0; j < 4; ++j) {
        float4 v;
        v.x = ya[4 * j + 0] * inva; v.y = ya[4 * j + 1] * inva;
        v.z = ya[4 * j + 2] * inva; v.w = ya[4 * j + 3] * inva;
        oa[j] = v;
        float4 u;
        u.x = yb[4 * j + 0] * invb; u.y = yb[4 * j + 1] * invb;
        u.z = yb[4 * j + 2] * invb; u.w = yb[4 * j + 3] * invb;
        ob[j] = u;
    }
}

extern "C" void kernel_launch(void* const* d_in, const int* in_sizes, int n_in,
                              void* d_out, int out_size, void* d_ws, size_t ws_size,
                              hipStream_t stream) {
    const float* qkv = (const float*)d_in[0];
    float* out = (float*)d_out;
    float* ws = (float*)d_ws;

    const size_t slot_bytes = (size_t)SLOT * 4;
    const int avail = (int)(ws_size / slot_bytes) - 1;  // partial slots available
    int nch = 32;
    while (nch > 1 && avail < nch) nch >>= 1;

    if (nch >= 2) {
        phase1_kernel<<<dim3(nch, NBH), dim3(P1T), 0, stream>>>(qkv, ws, 0);
        reduce_kernel<<<dim3(SLOT / 4 / 256), dim3(256), 0, stream>>>(ws, nch);
    } else {
        phase1_kernel<<<dim3(1, NBH), dim3(P1T), 0, stream>>>(qkv, ws, 1);
    }
    phase2_kernel<<<dim3(NTOK / 512, NBH, 2), dim3(256), 0, stream>>>(qkv, ws, out);
}

// Round 7
// 130.103 us; speedup vs baseline: 1.3756x; 1.3756x over previous
//
#include <hip/hip_runtime.h>

#define NTOK 4096
#define DIM 32
#define NBH 32              // B*H
#define NPAIR2 528          // upper triangle incl. diagonal of 32x32
#define NROWS 560           // + 32 kv1 rows
#define BHF (NROWS * 32 + 64)       // floats per bh: rows + ksum(32) + vsum(32) = 17984
#define SLOT (NBH * BHF)            // 575488 floats per slot (2.30 MB)
#define TILE 64
#define LSTR 36             // padded LDS row stride; col 32 = 1.0 (kv1), col 34 = 0.0 (dummy)
#define P1T 320             // phase1 threads (5 waves); rows: t and t+320

#define KCH 18              // K-chunks for phase2 MFMA (K = 576)
#define PK_U32 (NBH * KCH * 1024)   // packed B-frag u32 count = 589,824
#define P2TOK 128

typedef __attribute__((ext_vector_type(8))) short bf16x8;
typedef __attribute__((ext_vector_type(4))) float f32x4;
typedef __attribute__((ext_vector_type(4))) unsigned u32x4;

__device__ __forceinline__ int tri_start(int d) { return (d * (65 - d)) >> 1; }

__device__ __forceinline__ int tri_decode_d(int p) {
    int d = (int)((65.0f - sqrtf((float)(4225 - 8 * p))) * 0.5f);
    if (d < 0) d = 0;
    if (d > 31) d = 31;
    while (d < 31 && tri_start(d + 1) <= p) ++d;
    while (d > 0 && tri_start(d) > p) --d;
    return d;
}

__device__ __forceinline__ void row_operands(int row, int& ia, int& ib) {
    if (row < NPAIR2) {
        const int d = tri_decode_d(row);
        ia = d; ib = d + (row - tri_start(d));
    } else if (row < NROWS) {
        ia = row - NPAIR2; ib = 32;
    } else {
        ia = 34; ib = 34;
    }
}

__device__ __forceinline__ unsigned short f2bf(float x) {
    unsigned u = __builtin_bit_cast(unsigned, x);
    return (unsigned short)((u + 0x7FFFu + ((u >> 16) & 1u)) >> 16);
}
__device__ __forceinline__ float bf2f(unsigned short u) {
    return __builtin_bit_cast(float, (unsigned)u << 16);
}

// ---------------- Phase 1 (unchanged): per (bh, chunk) partial weight rows ---------------
__global__ __launch_bounds__(P1T) void phase1_kernel(const float* __restrict__ qkv,
                                                     float* __restrict__ ws, int direct) {
    const int chunk = blockIdx.x;
    const int bh = blockIdx.y;
    const int CHt = NTOK / gridDim.x;
    const int t = threadIdx.x;
    const float* kptr = qkv + (size_t)(NBH + bh) * (NTOK * DIM);
    const float* vptr = qkv + (size_t)(2 * NBH + bh) * (NTOK * DIM);
    float* base = ws + (direct ? (size_t)0 : (size_t)SLOT * (1 + chunk)) + (size_t)bh * BHF;

    __shared__ __align__(16) float sk[TILE][LSTR];
    __shared__ __align__(16) float sv[TILE][LSTR];

    int ia0, ib0, ia1, ib1;
    row_operands(t, ia0, ib0);
    row_operands(t + P1T, ia1, ib1);
    const float* a0 = &sk[0][ia0];
    const float* b0 = &sk[0][ib0];
    const float* a1 = &sk[0][ia1];
    const float* b1 = &sk[0][ib1];
    const float* sums = (t >= 288) ? &sv[0][t - 288] : ((t >= 256) ? &sk[0][t - 256] : &sk[0][0]);

    float acc0[32], acc1[32];
#pragma unroll
    for (int f = 0; f < 32; ++f) { acc0[f] = 0.f; acc1[f] = 0.f; }
    float accs = 0.f;

    if (t < 64) sk[t][32] = 1.0f;
    else if (t < 128) sk[t - 64][34] = 0.0f;

    const int n0 = chunk * CHt;
    for (int nt = 0; nt < CHt; nt += TILE) {
        __syncthreads();
        if (t < 256) {
            const float4* kg4 = (const float4*)(kptr + (size_t)(n0 + nt) * DIM);
            const float4* vg4 = (const float4*)(vptr + (size_t)(n0 + nt) * DIM);
            const int i0 = t, i1 = t + 256;
            *(float4*)&sk[i0 >> 3][(i0 & 7) << 2] = kg4[i0];
            *(float4*)&sk[i1 >> 3][(i1 & 7) << 2] = kg4[i1];
            *(float4*)&sv[i0 >> 3][(i0 & 7) << 2] = vg4[i0];
            *(float4*)&sv[i1 >> 3][(i1 & 7) << 2] = vg4[i1];
        }
        __syncthreads();
#pragma unroll 2
        for (int nn = 0; nn < TILE; ++nn) {
            const float s0 = a0[nn * LSTR] * b0[nn * LSTR];
            const float s1 = a1[nn * LSTR] * b1[nn * LSTR];
            const float* vrow = vptr + (size_t)(n0 + nt + nn) * DIM;
            float4 w[8];
#pragma unroll
            for (int j = 0; j < 8; ++j) w[j] = ((const float4*)vrow)[j];
#pragma unroll
            for (int j = 0; j < 8; ++j) {
                acc0[4 * j + 0] += s0 * w[j].x; acc0[4 * j + 1] += s0 * w[j].y;
                acc0[4 * j + 2] += s0 * w[j].z; acc0[4 * j + 3] += s0 * w[j].w;
                acc1[4 * j + 0] += s1 * w[j].x; acc1[4 * j + 1] += s1 * w[j].y;
                acc1[4 * j + 2] += s1 * w[j].z; acc1[4 * j + 3] += s1 * w[j].w;
            }
            if (t >= 256) accs += sums[nn * LSTR];
        }
    }

    {
        float* dst = base + (size_t)t * 32;
#pragma unroll
        for (int j = 0; j < 8; ++j) {
            float4 v; v.x = acc0[4 * j]; v.y = acc0[4 * j + 1];
            v.z = acc0[4 * j + 2]; v.w = acc0[4 * j + 3];
            ((float4*)dst)[j] = v;
        }
    }
    if (t < 240) {
        float* dst = base + (size_t)(t + P1T) * 32;
#pragma unroll
        for (int j = 0; j < 8; ++j) {
            float4 v; v.x = acc1[4 * j]; v.y = acc1[4 * j + 1];
            v.z = acc1[4 * j + 2]; v.w = acc1[4 * j + 3];
            ((float4*)dst)[j] = v;
        }
    }
    if (t >= 256) base[NROWS * 32 + (t - 256)] = accs;
}

// ---------------- reduce slots 1..nch into slot 0 ----------------
__global__ __launch_bounds__(256) void reduce_kernel(float* __restrict__ ws, int nch) {
    const int i = blockIdx.x * 256 + threadIdx.x;
    if (i >= SLOT / 4) return;
    float4 a = {0.f, 0.f, 0.f, 0.f};
    for (int c = 1; c <= nch; ++c) {
        const float4 p = ((const float4*)(ws + (size_t)SLOT * c))[i];
        a.x += p.x; a.y += p.y; a.z += p.z; a.w += p.w;
    }
    ((float4*)ws)[i] = a;
}

// ---------------- prep: pack W (bf16 hi/lo split) into B-fragment layout ----------------
// K-order: kc0: kv1 rows d=j. kc1: j=0 vsum; j in 1..15 zero; j>=16 pair (j-16, j).
// kc>=2: o=kc-2, pair (j, (j+o)&31) -> triangle row, coeff 0.5 on diag (o==0).
// Layout: bpk[((bh*18+kc)*2+fh)*512 + hl*256 + l*4 + r] ; u32 = bf16(k even)|bf16(k odd)<<16
__global__ __launch_bounds__(256) void prep_kernel(const float* __restrict__ ws,
                                                   unsigned* __restrict__ bpk) {
    const int idx = blockIdx.x * 256 + threadIdx.x;
    if (idx >= PK_U32) return;
    const int r = idx & 3;
    const int l = (idx >> 2) & 63;
    const int hl = (idx >> 8) & 1;
    const int fh = (idx >> 9) & 1;
    const int kc = (idx >> 10) % KCH;
    const int bh = idx / (KCH * 1024);
    const float* base = ws + (size_t)bh * BHF;
    const int f = fh * 16 + (l & 15);
    const int k0 = kc * 32 + ((l >> 4) << 3) + 2 * r;
    unsigned outw = 0;
#pragma unroll
    for (int s = 0; s < 2; ++s) {
        const int k = k0 + s;
        const int j = k & 31;
        float val = 0.f;
        if (kc == 0) {
            val = base[(size_t)(NPAIR2 + j) * 32 + f];
        } else if (kc == 1) {
            if (j == 0) val = base[NROWS * 32 + 32 + f];
            else if (j >= 16) { const int d = j - 16; val = base[(size_t)(tri_start(d) + 16) * 32 + f]; }
        } else {
            const int o = kc - 2;
            const int d = j, e = (j + o) & 31;
            const int mn = (d < e) ? d : e;
            const int mx = (d < e) ? e : d;
            const float c = (o == 0) ? 0.5f : 1.0f;
            val = c * base[(size_t)(tri_start(mn) + (mx - mn)) * 32 + f];
        }
        const unsigned short hb = f2bf(val);
        unsigned short bits = hb;
        if (hl == 1) bits = f2bf(val - bf2f(hb));
        outw |= (unsigned)bits << (16 * s);
    }
    bpk[idx] = outw;
}

// ---------------- phase 2: y = Phi * W via split-bf16 MFMA ----------------
#define EMIT_PHI() do { \
    unsigned hh[16], llw[16]; \
    _Pragma("unroll") \
    for (int kp = 0; kp < 16; ++kp) { \
        const float p0 = phi[2 * kp], p1 = phi[2 * kp + 1]; \
        const unsigned short h0 = f2bf(p0), h1 = f2bf(p1); \
        const float l0 = p0 - bf2f(h0), l1 = p1 - bf2f(h1); \
        hh[kp] = (unsigned)h0 | ((unsigned)h1 << 16); \
        llw[kp] = (unsigned)f2bf(l0) | ((unsigned)f2bf(l1) << 16); \
    } \
    _Pragma("unroll") \
    for (int c4 = 0; c4 < 4; ++c4) { \
        u32x4 vh = {hh[4*c4], hh[4*c4+1], hh[4*c4+2], hh[4*c4+3]}; \
        u32x4 vl = {llw[4*c4], llw[4*c4+1], llw[4*c4+2], llw[4*c4+3]}; \
        *(u32x4*)&sph[t * 20 + c4 * 4] = vh; \
        *(u32x4*)&spl[t * 20 + c4 * 4] = vl; \
    } \
} while (0)

#define MFMA_CHUNK(KC) do { \
    const unsigned* bc = bbase + (size_t)(KC) * 1024; \
    const bf16x8 Bh0 = __builtin_bit_cast(bf16x8, *(const u32x4*)(bc + 0   + l * 4)); \
    const bf16x8 Bl0 = __builtin_bit_cast(bf16x8, *(const u32x4*)(bc + 256 + l * 4)); \
    const bf16x8 Bh1 = __builtin_bit_cast(bf16x8, *(const u32x4*)(bc + 512 + l * 4)); \
    const bf16x8 Bl1 = __builtin_bit_cast(bf16x8, *(const u32x4*)(bc + 768 + l * 4)); \
    _Pragma("unroll") \
    for (int T = 0; T < 4; ++T) { \
        const int ro = (wbase + T * 16 + arow) * 20 + acol; \
        const bf16x8 Ah = __builtin_bit_cast(bf16x8, *(const u32x4*)&sph[ro]); \
        const bf16x8 Al = __builtin_bit_cast(bf16x8, *(const u32x4*)&spl[ro]); \
        acc[T][0] = __builtin_amdgcn_mfma_f32_16x16x32_bf16(Ah, Bh0, acc[T][0], 0, 0, 0); \
        acc[T][0] = __builtin_amdgcn_mfma_f32_16x16x32_bf16(Al, Bh0, acc[T][0], 0, 0, 0); \
        acc[T][0] = __builtin_amdgcn_mfma_f32_16x16x32_bf16(Ah, Bl0, acc[T][0], 0, 0, 0); \
        acc[T][1] = __builtin_amdgcn_mfma_f32_16x16x32_bf16(Ah, Bh1, acc[T][1], 0, 0, 0); \
        acc[T][1] = __builtin_amdgcn_mfma_f32_16x16x32_bf16(Al, Bh1, acc[T][1], 0, 0, 0); \
        acc[T][1] = __builtin_amdgcn_mfma_f32_16x16x32_bf16(Ah, Bl1, acc[T][1], 0, 0, 0); \
    } \
} while (0)

__global__ __launch_bounds__(P2TOK) void phase2m_kernel(const float* __restrict__ qkv,
                                                        const float* __restrict__ ws,
                                                        const unsigned* __restrict__ bpk,
                                                        float* __restrict__ out) {
    const int bh = blockIdx.y;
    const int tok0 = blockIdx.x * P2TOK;
    const int t = threadIdx.x;
    const int l = t & 63;
    const int wbase = (t >> 6) << 6;      // token base of this wave within block
    const int arow = l & 15;
    const int acol = (l >> 4) << 2;

    __shared__ unsigned sph[P2TOK * 20];
    __shared__ unsigned spl[P2TOK * 20];
    __shared__ float sinv[P2TOK];

    // load q for my token
    float q[32];
    {
        const float4* q4 = (const float4*)(qkv + ((size_t)bh * NTOK + tok0 + t) * DIM);
#pragma unroll
        for (int i = 0; i < 8; ++i) {
            const float4 v = q4[i];
            q[4 * i + 0] = v.x; q[4 * i + 1] = v.y; q[4 * i + 2] = v.z; q[4 * i + 3] = v.w;
        }
    }
    // y_norm (ksum uniform -> s_loads)
    {
        const float* ks = ws + (size_t)bh * BHF + NROWS * 32;
        float qk = 0.f;
#pragma unroll
        for (int d = 0; d < 32; ++d) qk += q[d] * ks[d];
        sinv[t] = 1.0f / (0.5f * qk * qk + qk + 1.0f);
    }

    f32x4 acc[4][2];
#pragma unroll
    for (int T = 0; T < 4; ++T)
#pragma unroll
        for (int fh = 0; fh < 2; ++fh) acc[T][fh] = (f32x4){0.f, 0.f, 0.f, 0.f};

    const unsigned* bbase = bpk + (size_t)bh * (KCH * 1024);

    // chunk 0: kv1 -> phi_j = q_j
    {
        float phi[32];
#pragma unroll
        for (int j2 = 0; j2 < 32; ++j2) phi[j2] = q[j2];
        EMIT_PHI();
        MFMA_CHUNK(0);
    }
    // chunk 1: vsum (phi=1), zeros, pairs (d, d+16)
    {
        float phi[32];
        phi[0] = 1.0f;
#pragma unroll
        for (int j2 = 1; j2 < 16; ++j2) phi[j2] = 0.f;
#pragma unroll
        for (int d2 = 0; d2 < 16; ++d2) phi[16 + d2] = q[d2] * q[d2 + 16];
        EMIT_PHI();
        MFMA_CHUNK(1);
    }
    // chunks 2..17: offset o = kc-2, phi_j = q_j * qr_j, rotate qr each chunk
    {
        float qr[32];
#pragma unroll
        for (int j2 = 0; j2 < 32; ++j2) qr[j2] = q[j2];
#pragma unroll 1
        for (int kc = 2; kc < KCH; ++kc) {
            float phi[32];
#pragma unroll
            for (int j2 = 0; j2 < 32; ++j2) phi[j2] = q[j2] * qr[j2];
            EMIT_PHI();
            MFMA_CHUNK(kc);
            const float tmp = qr[0];
#pragma unroll
            for (int j2 = 0; j2 < 31; ++j2) qr[j2] = qr[j2 + 1];
            qr[31] = tmp;
        }
    }

    // epilogue: scale by 1/y_norm and store (D layout: col=l&15, row=4*(l>>4)+r)
#pragma unroll
    for (int T = 0; T < 4; ++T) {
#pragma unroll
        for (int r = 0; r < 4; ++r) {
            const int row = wbase + T * 16 + ((l >> 4) << 2) + r;
            const float iv = sinv[row];
            float* op = out + ((size_t)bh * NTOK + tok0 + row) * DIM + (l & 15);
            op[0]  = acc[T][0][r] * iv;
            op[16] = acc[T][1][r] * iv;
        }
    }
}

// ---------------- old phase2 (fallback when workspace is tiny) ----------------
__global__ __launch_bounds__(256) void phase2_kernel(const float* __restrict__ qkv,
                                                     const float* __restrict__ ws,
                                                     float* __restrict__ out) {
    const int bh = blockIdx.y;
    const int f0 = blockIdx.z << 4;
    const int t = threadIdx.x;
    const int tok0 = blockIdx.x * 256;
    const float* qptr = qkv + (size_t)bh * (NTOK * DIM) + (size_t)tok0 * DIM;
    const float* base = ws + (size_t)bh * BHF;
    const float* ksum = base + NROWS * 32;
    const float* vsum = ksum + 32;

    __shared__ float qT[32][256];
    {
        const float4* q4 = (const float4*)qptr + (size_t)t * 8;
#pragma unroll
        for (int i = 0; i < 8; ++i) {
            const float4 v = q4[i];
            qT[4 * i + 0][t] = v.x; qT[4 * i + 1][t] = v.y;
            qT[4 * i + 2][t] = v.z; qT[4 * i + 3][t] = v.w;
        }
    }
    __syncthreads();

    float y[16];
#pragma unroll
    for (int j = 0; j < 4; ++j) {
        const float4 v = *(const float4*)(vsum + f0 + 4 * j);
        y[4 * j + 0] = v.x; y[4 * j + 1] = v.y; y[4 * j + 2] = v.z; y[4 * j + 3] = v.w;
    }
    float qk = 0.f;
    const float* rowp = base + f0;
#pragma unroll 1
    for (int d = 0; d < 32; ++d) {
        const float qd = qT[d][t];
        qk += qd * ksum[d];
        {
            const float s = 0.5f * qd * qd;
            const float4* r = (const float4*)rowp;
#pragma unroll
            for (int j = 0; j < 4; ++j) {
                const float4 w = r[j];
                y[4 * j + 0] += s * w.x; y[4 * j + 1] += s * w.y;
                y[4 * j + 2] += s * w.z; y[4 * j + 3] += s * w.w;
            }
            rowp += 32;
        }
#pragma unroll 4
        for (int e = d + 1; e < 32; ++e) {
            const float s = qd * qT[e][t];
            const float4* r = (const float4*)rowp;
#pragma unroll
            for (int j = 0; j < 4; ++j) {
                const float4 w = r[j];
                y[4 * j + 0] += s * w.x; y[4 * j + 1] += s * w.y;
                y[4 * j + 2] += s * w.z; y[4 * j + 3] += s * w.w;
            }
            rowp += 32;
        }
    }
#pragma unroll 4
    for (int d = 0; d < 32; ++d) {
        const float qd = qT[d][t];
        const float4* r = (const float4*)rowp;
#pragma unroll
        for (int j = 0; j < 4; ++j) {
            const float4 w = r[j];
            y[4 * j + 0] += qd * w.x; y[4 * j + 1] += qd * w.y;
            y[4 * j + 2] += qd * w.z; y[4 * j + 3] += qd * w.w;
        }
        rowp += 32;
    }
    const float inv = 1.0f / (0.5f * qk * qk + qk + 1.0f);
    float4* o4 = (float4*)(out + (size_t)bh * (NTOK * DIM) + (size_t)(tok0 + t) * DIM + f0);
#pragma unroll
    for (int j = 0; j < 4; ++j) {
        float4 v;
        v.x = y[4 * j + 0] * inv; v.y = y[4 * j + 1] * inv;
        v.z = y[4 * j + 2] * inv; v.w = y[4 * j + 3] * inv;
        o4[j] = v;
    }
}

extern "C" void kernel_launch(void* const* d_in, const int* in_sizes, int n_in,
                              void* d_out, int out_size, void* d_ws, size_t ws_size,
                              hipStream_t stream) {
    const float* qkv = (const float*)d_in[0];
    float* out = (float*)d_out;
    float* ws = (float*)d_ws;

    const size_t slot_bytes = (size_t)SLOT * 4;
    const int avail = (int)(ws_size / slot_bytes) - 1;
    int nch = 32;
    while (nch > 1 && avail < nch) nch >>= 1;

    if (nch >= 2) {
        phase1_kernel<<<dim3(nch, NBH), dim3(P1T), 0, stream>>>(qkv, ws, 0);
        reduce_kernel<<<dim3(SLOT / 4 / 256), dim3(256), 0, stream>>>(ws, nch);
        unsigned* bpk = (unsigned*)(ws + SLOT);   // slots 1+ are dead after reduce
        prep_kernel<<<dim3((PK_U32 + 255) / 256), dim3(256), 0, stream>>>(ws, bpk);
        phase2m_kernel<<<dim3(NTOK / P2TOK, NBH), dim3(P2TOK), 0, stream>>>(qkv, ws, bpk, out);
    } else {
        phase1_kernel<<<dim3(1, NBH), dim3(P1T), 0, stream>>>(qkv, ws, 1);
        phase2_kernel<<<dim3(NTOK / 256, NBH, 2), dim3(256), 0, stream>>>(qkv, ws, out);
    }
}

// Round 9
// 74.929 us; speedup vs baseline: 2.3885x; 1.7363x over previous
//
#include <hip/hip_runtime.h>

#define NTOK 4096
#define DIM 32
#define NBH 32              // B*H

// ---------- MFMA phase1 layout ----------
#define BHF1 18496          // 576 rows * 32 f + 64 sums
#define SLOT1 591872        // NBH * BHF1 floats (2.37 MB)
#define SUMOFF1 18432       // 576*32
#define KCH1 16             // phase1 token chunks (256 tok each)
#define TSF 260             // skT token stride in fp32 (1040 B, 16B-aligned)
#define TSH 264             // svT token stride in fp16 (528 B, 16B-aligned)

#define KCH 18              // phase2 K-chunks (K = 576)
#define PK_U32 (NBH * KCH * 1024)   // 589,824 packed B-frag u32
#define PK_HALF (PK_U32 / 2)        // 294,912
#define P2TOK 128

// ---------- OLD (fallback) layout ----------
#define NPAIR2 528
#define NROWS 560
#define BHF (NROWS * 32 + 64)       // 17984
#define SLOT (NBH * BHF)            // 575488
#define TILE 64
#define LSTR 36
#define P1T 320

typedef __attribute__((ext_vector_type(8))) short bf16x8;
typedef __attribute__((ext_vector_type(8))) _Float16 f16x8;
typedef __attribute__((ext_vector_type(4))) float f32x4;
typedef __attribute__((ext_vector_type(4))) unsigned u32x4;

__device__ __forceinline__ int tri_start(int d) { return (d * (65 - d)) >> 1; }

__device__ __forceinline__ int tri_decode_d(int p) {
    int d = (int)((65.0f - sqrtf((float)(4225 - 8 * p))) * 0.5f);
    if (d < 0) d = 0;
    if (d > 31) d = 31;
    while (d < 31 && tri_start(d + 1) <= p) ++d;
    while (d > 0 && tri_start(d) > p) --d;
    return d;
}

__device__ __forceinline__ void row_operands(int row, int& ia, int& ib) {
    if (row < NPAIR2) {
        const int d = tri_decode_d(row);
        ia = d; ib = d + (row - tri_start(d));
    } else if (row < NROWS) {
        ia = row - NPAIR2; ib = 32;
    } else {
        ia = 34; ib = 34;
    }
}

__device__ __forceinline__ unsigned short f2bf(float x) {
    unsigned u = __builtin_bit_cast(unsigned, x);
    return (unsigned short)((u + 0x7FFFu + ((u >> 16) & 1u)) >> 16);
}
__device__ __forceinline__ float bf2f(unsigned short u) {
    return __builtin_bit_cast(float, (unsigned)u << 16);
}

// fp32[8] -> f16 hi/lo fragments (hi = RTN, lo = exact residual; dropped ~2^-22 rel)
__device__ __forceinline__ void split8(const float* p, f16x8& hi, f16x8& lo) {
#pragma unroll
    for (int j = 0; j < 8; ++j) {
        const _Float16 h = (_Float16)p[j];
        hi[j] = h;
        lo[j] = (_Float16)(p[j] - (float)h);
    }
}

#define MF(A, B, C) __builtin_amdgcn_mfma_f32_16x16x32_f16((A), (B), (C), 0, 0, 0)

// =================== Phase 1 (MFMA, fp32-exact A-products) ===================
// W row R = o*32+d (o=0..16, pair (d,(d+o)&31)); R = 544+d: kv1. Sums at SUMOFF1.
// Wave w: offsets {w, w+4, w+8, w+12} + special (w0: o16, w1: kv1, w2: ksum, w3: vsum).
// A-frags: fp32 k-products computed in registers, split f16 hi/lo, 3-pass MFMA.
__global__ __launch_bounds__(256) void phase1m_kernel(const float* __restrict__ qkv,
                                                      float* __restrict__ ws) {
    const int chunk = blockIdx.x;
    const int bh = blockIdx.y;
    const int t = threadIdx.x;
    const int w = t >> 6, l = t & 63, g = l >> 4, c16 = l & 15;

    __shared__ float skT[32 * TSF];        // 33.3 KB
    __shared__ _Float16 svhiT[32 * TSH];   // 16.9 KB
    __shared__ _Float16 svloT[32 * TSH];   // 16.9 KB

    // ---- stage 256 tokens: k fp32 transposed, v f16 hi/lo transposed ----
    {
        const float4* kg4 = (const float4*)(qkv + (size_t)(NBH + bh) * (NTOK * DIM) + (size_t)chunk * 256 * DIM);
        const float4* vg4 = (const float4*)(qkv + (size_t)(2 * NBH + bh) * (NTOK * DIM) + (size_t)chunk * 256 * DIM);
#pragma unroll
        for (int j = 0; j < 8; ++j) {
            const int i = t + 256 * j;
            const int tok = i >> 3, dbase = (i & 7) << 2;
            const float4 kf = kg4[i];
            const float4 vf = vg4[i];
            const float ke[4] = {kf.x, kf.y, kf.z, kf.w};
            const float ve[4] = {vf.x, vf.y, vf.z, vf.w};
#pragma unroll
            for (int c = 0; c < 4; ++c) {
                skT[(dbase + c) * TSF + tok] = ke[c];
                const _Float16 h = (_Float16)ve[c];
                svhiT[(dbase + c) * TSH + tok] = h;
                svloT[(dbase + c) * TSH + tok] = (_Float16)(ve[c] - (float)h);
            }
        }
    }
    __syncthreads();

    f32x4 acc[4][2][2];
    f32x4 accS[2][2];
#pragma unroll
    for (int i = 0; i < 4; ++i)
#pragma unroll
        for (int m = 0; m < 2; ++m)
#pragma unroll
            for (int fh = 0; fh < 2; ++fh) acc[i][m][fh] = (f32x4){0.f, 0.f, 0.f, 0.f};
#pragma unroll
    for (int m = 0; m < 2; ++m)
#pragma unroll
        for (int fh = 0; fh < 2; ++fh) accS[m][fh] = (f32x4){0.f, 0.f, 0.f, 0.f};

    const f16x8 ones = {(_Float16)1.f, (_Float16)1.f, (_Float16)1.f, (_Float16)1.f,
                        (_Float16)1.f, (_Float16)1.f, (_Float16)1.f, (_Float16)1.f};

#pragma unroll 1
    for (int n0 = 0; n0 < 256; n0 += 32) {
        const int sl = n0 + 8 * g;
        float a0[8], a1[8];
        *(float4*)&a0[0] = *(const float4*)(skT + c16 * TSF + sl);
        *(float4*)&a0[4] = *(const float4*)(skT + c16 * TSF + sl + 4);
        *(float4*)&a1[0] = *(const float4*)(skT + (16 + c16) * TSF + sl);
        *(float4*)&a1[4] = *(const float4*)(skT + (16 + c16) * TSF + sl + 4);
        const f16x8 Bh0 = *(const f16x8*)(svhiT + c16 * TSH + sl);
        const f16x8 Bh1 = *(const f16x8*)(svhiT + (16 + c16) * TSH + sl);
        const f16x8 Bl0 = *(const f16x8*)(svloT + c16 * TSH + sl);
        const f16x8 Bl1 = *(const f16x8*)(svloT + (16 + c16) * TSH + sl);

#pragma unroll
        for (int i = 0; i < 4; ++i) {
            const int o = w + 4 * i;
            const int r0 = ((c16 + o) & 31) * TSF;
            const int r1 = ((16 + c16 + o) & 31) * TSF;
            float e0[8], e1[8], p0[8], p1[8];
            *(float4*)&e0[0] = *(const float4*)(skT + r0 + sl);
            *(float4*)&e0[4] = *(const float4*)(skT + r0 + sl + 4);
            *(float4*)&e1[0] = *(const float4*)(skT + r1 + sl);
            *(float4*)&e1[4] = *(const float4*)(skT + r1 + sl + 4);
#pragma unroll
            for (int j = 0; j < 8; ++j) { p0[j] = a0[j] * e0[j]; p1[j] = a1[j] * e1[j]; }
            f16x8 A0h, A0l, A1h, A1l;
            split8(p0, A0h, A0l);
            split8(p1, A1h, A1l);
            acc[i][0][0] = MF(A0h, Bh0, acc[i][0][0]);
            acc[i][0][0] = MF(A0l, Bh0, acc[i][0][0]);
            acc[i][0][0] = MF(A0h, Bl0, acc[i][0][0]);
            acc[i][0][1] = MF(A0h, Bh1, acc[i][0][1]);
            acc[i][0][1] = MF(A0l, Bh1, acc[i][0][1]);
            acc[i][0][1] = MF(A0h, Bl1, acc[i][0][1]);
            acc[i][1][0] = MF(A1h, Bh0, acc[i][1][0]);
            acc[i][1][0] = MF(A1l, Bh0, acc[i][1][0]);
            acc[i][1][0] = MF(A1h, Bl0, acc[i][1][0]);
            acc[i][1][1] = MF(A1h, Bh1, acc[i][1][1]);
            acc[i][1][1] = MF(A1l, Bh1, acc[i][1][1]);
            acc[i][1][1] = MF(A1h, Bl1, acc[i][1][1]);
        }

        if (w == 0) {            // o=16 (duplicate-symmetric pair rows)
            float p[8];
#pragma unroll
            for (int j = 0; j < 8; ++j) p[j] = a0[j] * a1[j];
            f16x8 Ah, Al;
            split8(p, Ah, Al);
            accS[0][0] = MF(Ah, Bh0, accS[0][0]);
            accS[0][0] = MF(Al, Bh0, accS[0][0]);
            accS[0][0] = MF(Ah, Bl0, accS[0][0]);
            accS[0][1] = MF(Ah, Bh1, accS[0][1]);
            accS[0][1] = MF(Al, Bh1, accS[0][1]);
            accS[0][1] = MF(Ah, Bl1, accS[0][1]);
        } else if (w == 1) {     // kv1: A = k (split)
            f16x8 K0h, K0l, K1h, K1l;
            split8(a0, K0h, K0l);
            split8(a1, K1h, K1l);
            accS[0][0] = MF(K0h, Bh0, accS[0][0]);
            accS[0][0] = MF(K0l, Bh0, accS[0][0]);
            accS[0][0] = MF(K0h, Bl0, accS[0][0]);
            accS[0][1] = MF(K0h, Bh1, accS[0][1]);
            accS[0][1] = MF(K0l, Bh1, accS[0][1]);
            accS[0][1] = MF(K0h, Bl1, accS[0][1]);
            accS[1][0] = MF(K1h, Bh0, accS[1][0]);
            accS[1][0] = MF(K1l, Bh0, accS[1][0]);
            accS[1][0] = MF(K1h, Bl0, accS[1][0]);
            accS[1][1] = MF(K1h, Bh1, accS[1][1]);
            accS[1][1] = MF(K1l, Bh1, accS[1][1]);
            accS[1][1] = MF(K1h, Bl1, accS[1][1]);
        } else if (w == 2) {     // ksum: A = ones, B = k (split)
            f16x8 K0h, K0l, K1h, K1l;
            split8(a0, K0h, K0l);
            split8(a1, K1h, K1l);
            accS[0][0] = MF(ones, K0h, accS[0][0]);
            accS[0][0] = MF(ones, K0l, accS[0][0]);
            accS[1][0] = MF(ones, K1h, accS[1][0]);
            accS[1][0] = MF(ones, K1l, accS[1][0]);
        } else {                 // vsum: A = ones, B = v hi/lo
            accS[0][0] = MF(ones, Bh0, accS[0][0]);
            accS[0][0] = MF(ones, Bl0, accS[0][0]);
            accS[0][1] = MF(ones, Bh1, accS[0][1]);
            accS[0][1] = MF(ones, Bl1, accS[0][1]);
        }
    }

    // ---- store partials to slot (1+chunk) ----
    float* pb = ws + (size_t)SLOT1 * (1 + chunk) + (size_t)bh * BHF1;
#pragma unroll
    for (int i = 0; i < 4; ++i) {
        const int o = w + 4 * i;
#pragma unroll
        for (int m = 0; m < 2; ++m)
#pragma unroll
            for (int fh = 0; fh < 2; ++fh)
#pragma unroll
                for (int r = 0; r < 4; ++r) {
                    const int R = o * 32 + 16 * m + 4 * g + r;
                    pb[(size_t)R * 32 + fh * 16 + c16] = acc[i][m][fh][r];
                }
    }
    if (w == 0) {
#pragma unroll
        for (int fh = 0; fh < 2; ++fh)
#pragma unroll
            for (int r = 0; r < 4; ++r) {
                const int R = 512 + 4 * g + r;
                pb[(size_t)R * 32 + fh * 16 + c16] = accS[0][fh][r];
                pb[(size_t)(R + 16) * 32 + fh * 16 + c16] = accS[0][fh][r];
            }
    } else if (w == 1) {
#pragma unroll
        for (int m = 0; m < 2; ++m)
#pragma unroll
            for (int fh = 0; fh < 2; ++fh)
#pragma unroll
                for (int r = 0; r < 4; ++r) {
                    const int R = 544 + 16 * m + 4 * g + r;
                    pb[(size_t)R * 32 + fh * 16 + c16] = accS[m][fh][r];
                }
    } else if (w == 2) {
        if (g == 0) {
            pb[SUMOFF1 + c16] = accS[0][0][0];
            pb[SUMOFF1 + 16 + c16] = accS[1][0][0];
        }
    } else {
        if (g == 0) {
            pb[SUMOFF1 + 32 + c16] = accS[0][0][0];
            pb[SUMOFF1 + 48 + c16] = accS[0][1][0];
        }
    }
}

// ============ reduce (16 slots) + prep (bf16 hi/lo B-frag pack) + sums ============
__global__ __launch_bounds__(256) void reduceprep_kernel(const float* __restrict__ ws,
                                                         float* __restrict__ wsw,
                                                         unsigned* __restrict__ bpk) {
    const int tid = blockIdx.x * 256 + threadIdx.x;
    if (tid < PK_HALF) {
        const int r = tid & 3;
        const int l = (tid >> 2) & 63;
        const int fh = (tid >> 8) & 1;
        const int kcbh = tid >> 9;
        const int kc = kcbh % KCH;
        const int bh = kcbh / KCH;
        const int f = fh * 16 + (l & 15);
        const int k0 = kc * 32 + ((l >> 4) << 3) + 2 * r;
        const float scale = (kc == 0 || kc == 16) ? 0.5f : 1.0f;
        float va = 0.f, vb = 0.f;
        const float* src = ws + (size_t)bh * BHF1 + (size_t)k0 * 32 + f;
#pragma unroll
        for (int c = 1; c <= KCH1; ++c) {
            va += src[(size_t)SLOT1 * c];
            vb += src[(size_t)SLOT1 * c + 32];
        }
        va *= scale; vb *= scale;
        const unsigned short ha = f2bf(va), hb = f2bf(vb);
        const unsigned short la = f2bf(va - bf2f(ha)), lb = f2bf(vb - bf2f(hb));
        const int widx = ((bh * KCH + kc) * 2 + fh) * 512 + l * 4 + r;
        bpk[widx] = (unsigned)ha | ((unsigned)hb << 16);
        bpk[widx + 256] = (unsigned)la | ((unsigned)lb << 16);
    } else {
        const int tid2 = tid - PK_HALF;
        if (tid2 < NBH * 64) {
            const int bh = tid2 >> 6;
            const int j = tid2 & 63;
            float s = 0.f;
            const float* src = ws + (size_t)bh * BHF1 + SUMOFF1 + j;
#pragma unroll
            for (int c = 1; c <= KCH1; ++c) s += src[(size_t)SLOT1 * c];
            wsw[(size_t)bh * BHF1 + SUMOFF1 + j] = s;
        }
    }
}

// =================== phase 2: y = Phi * W via split-bf16 MFMA ===================
#define EMIT_PHI() do { \
    unsigned hh[16], llw[16]; \
    _Pragma("unroll") \
    for (int kp = 0; kp < 16; ++kp) { \
        const float p0 = phi[2 * kp], p1 = phi[2 * kp + 1]; \
        const unsigned short h0 = f2bf(p0), h1 = f2bf(p1); \
        const float l0 = p0 - bf2f(h0), l1 = p1 - bf2f(h1); \
        hh[kp] = (unsigned)h0 | ((unsigned)h1 << 16); \
        llw[kp] = (unsigned)f2bf(l0) | ((unsigned)f2bf(l1) << 16); \
    } \
    _Pragma("unroll") \
    for (int c4 = 0; c4 < 4; ++c4) { \
        u32x4 vh = {hh[4*c4], hh[4*c4+1], hh[4*c4+2], hh[4*c4+3]}; \
        u32x4 vl = {llw[4*c4], llw[4*c4+1], llw[4*c4+2], llw[4*c4+3]}; \
        *(u32x4*)&sph[t * 20 + c4 * 4] = vh; \
        *(u32x4*)&spl[t * 20 + c4 * 4] = vl; \
    } \
} while (0)

#define MFMA_CHUNK(KC) do { \
    const unsigned* bc = bbase + (size_t)(KC) * 1024; \
    const bf16x8 Bh0 = __builtin_bit_cast(bf16x8, *(const u32x4*)(bc + 0   + l * 4)); \
    const bf16x8 Bl0 = __builtin_bit_cast(bf16x8, *(const u32x4*)(bc + 256 + l * 4)); \
    const bf16x8 Bh1 = __builtin_bit_cast(bf16x8, *(const u32x4*)(bc + 512 + l * 4)); \
    const bf16x8 Bl1 = __builtin_bit_cast(bf16x8, *(const u32x4*)(bc + 768 + l * 4)); \
    _Pragma("unroll") \
    for (int T = 0; T < 4; ++T) { \
        const int ro = (wbase + T * 16 + arow) * 20 + acol; \
        const bf16x8 Ah = __builtin_bit_cast(bf16x8, *(const u32x4*)&sph[ro]); \
        const bf16x8 Al = __builtin_bit_cast(bf16x8, *(const u32x4*)&spl[ro]); \
        acc[T][0] = __builtin_amdgcn_mfma_f32_16x16x32_bf16(Ah, Bh0, acc[T][0], 0, 0, 0); \
        acc[T][0] = __builtin_amdgcn_mfma_f32_16x16x32_bf16(Al, Bh0, acc[T][0], 0, 0, 0); \
        acc[T][0] = __builtin_amdgcn_mfma_f32_16x16x32_bf16(Ah, Bl0, acc[T][0], 0, 0, 0); \
        acc[T][1] = __builtin_amdgcn_mfma_f32_16x16x32_bf16(Ah, Bh1, acc[T][1], 0, 0, 0); \
        acc[T][1] = __builtin_amdgcn_mfma_f32_16x16x32_bf16(Al, Bh1, acc[T][1], 0, 0, 0); \
        acc[T][1] = __builtin_amdgcn_mfma_f32_16x16x32_bf16(Ah, Bl1, acc[T][1], 0, 0, 0); \
    } \
} while (0)

__global__ __launch_bounds__(P2TOK) void phase2m_kernel(const float* __restrict__ qkv,
                                                        const float* __restrict__ ws,
                                                        const unsigned* __restrict__ bpk,
                                                        float* __restrict__ out) {
    const int bh = blockIdx.y;
    const int tok0 = blockIdx.x * P2TOK;
    const int t = threadIdx.x;
    const int l = t & 63;
    const int wbase = (t >> 6) << 6;
    const int arow = l & 15;
    const int acol = (l >> 4) << 2;

    __shared__ unsigned sph[P2TOK * 20];
    __shared__ unsigned spl[P2TOK * 20];
    __shared__ float sinv[P2TOK];

    float q[32];
    {
        const float4* q4 = (const float4*)(qkv + ((size_t)bh * NTOK + tok0 + t) * DIM);
#pragma unroll
        for (int i = 0; i < 8; ++i) {
            const float4 v = q4[i];
            q[4 * i + 0] = v.x; q[4 * i + 1] = v.y; q[4 * i + 2] = v.z; q[4 * i + 3] = v.w;
        }
    }
    {
        const float* ks = ws + (size_t)bh * BHF1 + SUMOFF1;
        float qk = 0.f;
#pragma unroll
        for (int d = 0; d < 32; ++d) qk += q[d] * ks[d];
        sinv[t] = 1.0f / (0.5f * qk * qk + qk + 1.0f);
    }

    f32x4 acc[4][2];
#pragma unroll
    for (int T = 0; T < 4; ++T)
#pragma unroll
        for (int fh = 0; fh < 2; ++fh) acc[T][fh] = (f32x4){0.f, 0.f, 0.f, 0.f};

    const unsigned* bbase = bpk + (size_t)bh * (KCH * 1024);

    // chunks 0..16: offset o = kc, phi_j = q_j * q_{(j+kc)&31}
    {
        float qr[32];
#pragma unroll
        for (int j2 = 0; j2 < 32; ++j2) qr[j2] = q[j2];
#pragma unroll 1
        for (int kc = 0; kc < 17; ++kc) {
            float phi[32];
#pragma unroll
            for (int j2 = 0; j2 < 32; ++j2) phi[j2] = q[j2] * qr[j2];
            EMIT_PHI();
            MFMA_CHUNK(kc);
            const float tmp = qr[0];
#pragma unroll
            for (int j2 = 0; j2 < 31; ++j2) qr[j2] = qr[j2 + 1];
            qr[31] = tmp;
        }
    }
    // chunk 17: kv1, phi = q
    {
        float phi[32];
#pragma unroll
        for (int j2 = 0; j2 < 32; ++j2) phi[j2] = q[j2];
        EMIT_PHI();
        MFMA_CHUNK(17);
    }

    const float* vs = ws + (size_t)bh * BHF1 + SUMOFF1 + 32;
    const float vs0 = vs[l & 15];
    const float vs1 = vs[16 + (l & 15)];
#pragma unroll
    for (int T = 0; T < 4; ++T) {
#pragma unroll
        for (int r = 0; r < 4; ++r) {
            const int row = wbase + T * 16 + ((l >> 4) << 2) + r;
            const float iv = sinv[row];
            float* op = out + ((size_t)bh * NTOK + tok0 + row) * DIM + (l & 15);
            op[0]  = (acc[T][0][r] + vs0) * iv;
            op[16] = (acc[T][1][r] + vs1) * iv;
        }
    }
}

// =================== OLD fallback path (proven) ===================
__global__ __launch_bounds__(P1T) void phase1_kernel(const float* __restrict__ qkv,
                                                     float* __restrict__ ws, int direct) {
    const int chunk = blockIdx.x;
    const int bh = blockIdx.y;
    const int CHt = NTOK / gridDim.x;
    const int t = threadIdx.x;
    const float* kptr = qkv + (size_t)(NBH + bh) * (NTOK * DIM);
    const float* vptr = qkv + (size_t)(2 * NBH + bh) * (NTOK * DIM);
    float* base = ws + (direct ? (size_t)0 : (size_t)SLOT * (1 + chunk)) + (size_t)bh * BHF;

    __shared__ __align__(16) float sk[TILE][LSTR];
    __shared__ __align__(16) float sv[TILE][LSTR];

    int ia0, ib0, ia1, ib1;
    row_operands(t, ia0, ib0);
    row_operands(t + P1T, ia1, ib1);
    const float* a0 = &sk[0][ia0];
    const float* b0 = &sk[0][ib0];
    const float* a1 = &sk[0][ia1];
    const float* b1 = &sk[0][ib1];
    const float* sums = (t >= 288) ? &sv[0][t - 288] : ((t >= 256) ? &sk[0][t - 256] : &sk[0][0]);

    float acc0[32], acc1[32];
#pragma unroll
    for (int f = 0; f < 32; ++f) { acc0[f] = 0.f; acc1[f] = 0.f; }
    float accs = 0.f;

    if (t < 64) sk[t][32] = 1.0f;
    else if (t < 128) sk[t - 64][34] = 0.0f;

    const int n0 = chunk * CHt;
    for (int nt = 0; nt < CHt; nt += TILE) {
        __syncthreads();
        if (t < 256) {
            const float4* kg4 = (const float4*)(kptr + (size_t)(n0 + nt) * DIM);
            const float4* vg4 = (const float4*)(vptr + (size_t)(n0 + nt) * DIM);
            const int i0 = t, i1 = t + 256;
            *(float4*)&sk[i0 >> 3][(i0 & 7) << 2] = kg4[i0];
            *(float4*)&sk[i1 >> 3][(i1 & 7) << 2] = kg4[i1];
            *(float4*)&sv[i0 >> 3][(i0 & 7) << 2] = vg4[i0];
            *(float4*)&sv[i1 >> 3][(i1 & 7) << 2] = vg4[i1];
        }
        __syncthreads();
#pragma unroll 2
        for (int nn = 0; nn < TILE; ++nn) {
            const float s0 = a0[nn * LSTR] * b0[nn * LSTR];
            const float s1 = a1[nn * LSTR] * b1[nn * LSTR];
            const float* vrow = vptr + (size_t)(n0 + nt + nn) * DIM;
            float4 w[8];
#pragma unroll
            for (int j = 0; j < 8; ++j) w[j] = ((const float4*)vrow)[j];
#pragma unroll
            for (int j = 0; j < 8; ++j) {
                acc0[4 * j + 0] += s0 * w[j].x; acc0[4 * j + 1] += s0 * w[j].y;
                acc0[4 * j + 2] += s0 * w[j].z; acc0[4 * j + 3] += s0 * w[j].w;
                acc1[4 * j + 0] += s1 * w[j].x; acc1[4 * j + 1] += s1 * w[j].y;
                acc1[4 * j + 2] += s1 * w[j].z; acc1[4 * j + 3] += s1 * w[j].w;
            }
            if (t >= 256) accs += sums[nn * LSTR];
        }
    }

    {
        float* dst = base + (size_t)t * 32;
#pragma unroll
        for (int j = 0; j < 8; ++j) {
            float4 v; v.x = acc0[4 * j]; v.y = acc0[4 * j + 1];
            v.z = acc0[4 * j + 2]; v.w = acc0[4 * j + 3];
            ((float4*)dst)[j] = v;
        }
    }
    if (t < 240) {
        float* dst = base + (size_t)(t + P1T) * 32;
#pragma unroll
        for (int j = 0; j < 8; ++j) {
            float4 v; v.x = acc1[4 * j]; v.y = acc1[4 * j + 1];
            v.z = acc1[4 * j + 2]; v.w = acc1[4 * j + 3];
            ((float4*)dst)[j] = v;
        }
    }
    if (t >= 256) base[NROWS * 32 + (t - 256)] = accs;
}

__global__ __launch_bounds__(256) void phase2_kernel(const float* __restrict__ qkv,
                                                     const float* __restrict__ ws,
                                                     float* __restrict__ out) {
    const int bh = blockIdx.y;
    const int f0 = blockIdx.z << 4;
    const int t = threadIdx.x;
    const int tok0 = blockIdx.x * 256;
    const float* qptr = qkv + (size_t)bh * (NTOK * DIM) + (size_t)tok0 * DIM;
    const float* base = ws + (size_t)bh * BHF;
    const float* ksum = base + NROWS * 32;
    const float* vsum = ksum + 32;

    __shared__ float qT[32][256];
    {
        const float4* q4 = (const float4*)qptr + (size_t)t * 8;
#pragma unroll
        for (int i = 0; i < 8; ++i) {
            const float4 v = q4[i];
            qT[4 * i + 0][t] = v.x; qT[4 * i + 1][t] = v.y;
            qT[4 * i + 2][t] = v.z; qT[4 * i + 3][t] = v.w;
        }
    }
    __syncthreads();

    float y[16];
#pragma unroll
    for (int j = 0; j < 4; ++j) {
        const float4 v = *(const float4*)(vsum + f0 + 4 * j);
        y[4 * j + 0] = v.x; y[4 * j + 1] = v.y; y[4 * j + 2] = v.z; y[4 * j + 3] = v.w;
    }
    float qk = 0.f;
    const float* rowp = base + f0;
#pragma unroll 1
    for (int d = 0; d < 32; ++d) {
        const float qd = qT[d][t];
        qk += qd * ksum[d];
        {
            const float s = 0.5f * qd * qd;
            const float4* r = (const float4*)rowp;
#pragma unroll
            for (int j = 0; j < 4; ++j) {
                const float4 w = r[j];
                y[4 * j + 0] += s * w.x; y[4 * j + 1] += s * w.y;
                y[4 * j + 2] += s * w.z; y[4 * j + 3] += s * w.w;
            }
            rowp += 32;
        }
#pragma unroll 4
        for (int e = d + 1; e < 32; ++e) {
            const float s = qd * qT[e][t];
            const float4* r = (const float4*)rowp;
#pragma unroll
            for (int j = 0; j < 4; ++j) {
                const float4 w = r[j];
                y[4 * j + 0] += s * w.x; y[4 * j + 1] += s * w.y;
                y[4 * j + 2] += s * w.z; y[4 * j + 3] += s * w.w;
            }
            rowp += 32;
        }
    }
#pragma unroll 4
    for (int d = 0; d < 32; ++d) {
        const float qd = qT[d][t];
        const float4* r = (const float4*)rowp;
#pragma unroll
        for (int j = 0; j < 4; ++j) {
            const float4 w = r[j];
            y[4 * j + 0] += qd * w.x; y[4 * j + 1] += qd * w.y;
            y[4 * j + 2] += qd * w.z; y[4 * j + 3] += qd * w.w;
        }
        rowp += 32;
    }
    const float inv = 1.0f / (0.5f * qk * qk + qk + 1.0f);
    float4* o4 = (float4*)(out + (size_t)bh * (NTOK * DIM) + (size_t)(tok0 + t) * DIM + f0);
#pragma unroll
    for (int j = 0; j < 4; ++j) {
        float4 v;
        v.x = y[4 * j + 0] * inv; v.y = y[4 * j + 1] * inv;
        v.z = y[4 * j + 2] * inv; v.w = y[4 * j + 3] * inv;
        o4[j] = v;
    }
}

extern "C" void kernel_launch(void* const* d_in, const int* in_sizes, int n_in,
                              void* d_out, int out_size, void* d_ws, size_t ws_size,
                              hipStream_t stream) {
    const float* qkv = (const float*)d_in[0];
    float* out = (float*)d_out;
    float* ws = (float*)d_ws;

    const size_t need = ((size_t)(1 + KCH1) * SLOT1 + PK_U32) * 4;
    if (ws_size >= need) {
        unsigned* bpk = (unsigned*)(ws + (size_t)(1 + KCH1) * SLOT1);
        phase1m_kernel<<<dim3(KCH1, NBH), dim3(256), 0, stream>>>(qkv, ws);
        reduceprep_kernel<<<dim3((PK_HALF + NBH * 64) / 256), dim3(256), 0, stream>>>(ws, ws, bpk);
        phase2m_kernel<<<dim3(NTOK / P2TOK, NBH), dim3(P2TOK), 0, stream>>>(qkv, ws, bpk, out);
    } else {
        phase1_kernel<<<dim3(1, NBH), dim3(P1T), 0, stream>>>(qkv, ws, 1);
        phase2_kernel<<<dim3(NTOK / 256, NBH, 2), dim3(256), 0, stream>>>(qkv, ws, out);
    }
}

// Round 10
// 62.835 us; speedup vs baseline: 2.8482x; 1.1925x over previous
//
#include <hip/hip_runtime.h>

#define NTOK 4096
#define DIM 32
#define NBH 32              // B*H

// ---------- MFMA phase1 layout ----------
#define BHF1 18496          // 576 rows * 32 f + 64 sums
#define SLOT1 591872        // NBH * BHF1 floats (2.37 MB)
#define SUMOFF1 18432       // 576*32
#define KCH1 16             // phase1 token chunks (256 tok each)
#define TSF 260             // skT token stride in fp32 (1040 B, 16B-aligned)
#define TSH 264             // svT token stride in fp16 (528 B, 16B-aligned)

#define KCH 18              // phase2 K-chunks (K = 576)
#define PK_U32 (NBH * KCH * 1024)   // 589,824 packed B-frag u32
#define PK_HALF (PK_U32 / 2)        // 294,912
#define P2TOK 128

// ---------- OLD (fallback) layout ----------
#define NPAIR2 528
#define NROWS 560
#define BHF (NROWS * 32 + 64)       // 17984
#define SLOT (NBH * BHF)            // 575488
#define TILE 64
#define LSTR 36
#define P1T 320

typedef __attribute__((ext_vector_type(8))) short bf16x8;
typedef __attribute__((ext_vector_type(8))) _Float16 f16x8;
typedef __attribute__((ext_vector_type(4))) float f32x4;
typedef __attribute__((ext_vector_type(4))) unsigned u32x4;

__device__ __forceinline__ int tri_start(int d) { return (d * (65 - d)) >> 1; }

__device__ __forceinline__ int tri_decode_d(int p) {
    int d = (int)((65.0f - sqrtf((float)(4225 - 8 * p))) * 0.5f);
    if (d < 0) d = 0;
    if (d > 31) d = 31;
    while (d < 31 && tri_start(d + 1) <= p) ++d;
    while (d > 0 && tri_start(d) > p) --d;
    return d;
}

__device__ __forceinline__ void row_operands(int row, int& ia, int& ib) {
    if (row < NPAIR2) {
        const int d = tri_decode_d(row);
        ia = d; ib = d + (row - tri_start(d));
    } else if (row < NROWS) {
        ia = row - NPAIR2; ib = 32;
    } else {
        ia = 34; ib = 34;
    }
}

__device__ __forceinline__ unsigned short f2bf(float x) {
    unsigned u = __builtin_bit_cast(unsigned, x);
    return (unsigned short)((u + 0x7FFFu + ((u >> 16) & 1u)) >> 16);
}
__device__ __forceinline__ float bf2f(unsigned short u) {
    return __builtin_bit_cast(float, (unsigned)u << 16);
}

// fp32[8] -> f16 hi/lo fragments (hi = RTN, lo = exact residual)
__device__ __forceinline__ void split8(const float* p, f16x8& hi, f16x8& lo) {
#pragma unroll
    for (int j = 0; j < 8; ++j) {
        const _Float16 h = (_Float16)p[j];
        hi[j] = h;
        lo[j] = (_Float16)(p[j] - (float)h);
    }
}

#define MF(A, B, C) __builtin_amdgcn_mfma_f32_16x16x32_f16((A), (B), (C), 0, 0, 0)

// =================== Phase 1 (MFMA, fp32-exact A-products) ===================
// W row R = o*32+d (o=0..16, pair (d,(d+o)&31)); R = 544+d: kv1. Sums at SUMOFF1.
// Wave w: offsets {w, w+4, w+8, w+12} + special (w0: o16, w1: kv1, w2: ksum, w3: vsum).
__global__ __launch_bounds__(256) void phase1m_kernel(const float* __restrict__ qkv,
                                                      float* __restrict__ ws) {
    const int chunk = blockIdx.x;
    const int bh = blockIdx.y;
    const int t = threadIdx.x;
    const int w = t >> 6, l = t & 63, g = l >> 4, c16 = l & 15;

    __shared__ float skT[32 * TSF];        // 33.3 KB
    __shared__ _Float16 svhiT[32 * TSH];   // 16.9 KB
    __shared__ _Float16 svloT[32 * TSH];   // 16.9 KB

    // ---- stage 256 tokens: k fp32 transposed, v f16 hi/lo transposed ----
    {
        const float4* kg4 = (const float4*)(qkv + (size_t)(NBH + bh) * (NTOK * DIM) + (size_t)chunk * 256 * DIM);
        const float4* vg4 = (const float4*)(qkv + (size_t)(2 * NBH + bh) * (NTOK * DIM) + (size_t)chunk * 256 * DIM);
#pragma unroll
        for (int j = 0; j < 8; ++j) {
            const int i = t + 256 * j;
            const int tok = i >> 3, dbase = (i & 7) << 2;
            const float4 kf = kg4[i];
            const float4 vf = vg4[i];
            const float ke[4] = {kf.x, kf.y, kf.z, kf.w};
            const float ve[4] = {vf.x, vf.y, vf.z, vf.w};
#pragma unroll
            for (int c = 0; c < 4; ++c) {
                skT[(dbase + c) * TSF + tok] = ke[c];
                const _Float16 h = (_Float16)ve[c];
                svhiT[(dbase + c) * TSH + tok] = h;
                svloT[(dbase + c) * TSH + tok] = (_Float16)(ve[c] - (float)h);
            }
        }
    }
    __syncthreads();

    f32x4 acc[4][2][2];
    f32x4 accS[2][2];
#pragma unroll
    for (int i = 0; i < 4; ++i)
#pragma unroll
        for (int m = 0; m < 2; ++m)
#pragma unroll
            for (int fh = 0; fh < 2; ++fh) acc[i][m][fh] = (f32x4){0.f, 0.f, 0.f, 0.f};
#pragma unroll
    for (int m = 0; m < 2; ++m)
#pragma unroll
        for (int fh = 0; fh < 2; ++fh) accS[m][fh] = (f32x4){0.f, 0.f, 0.f, 0.f};

    const f16x8 ones = {(_Float16)1.f, (_Float16)1.f, (_Float16)1.f, (_Float16)1.f,
                        (_Float16)1.f, (_Float16)1.f, (_Float16)1.f, (_Float16)1.f};

#pragma unroll 1
    for (int n0 = 0; n0 < 256; n0 += 32) {
        const int sl = n0 + 8 * g;
        float a0[8], a1[8];
        *(float4*)&a0[0] = *(const float4*)(skT + c16 * TSF + sl);
        *(float4*)&a0[4] = *(const float4*)(skT + c16 * TSF + sl + 4);
        *(float4*)&a1[0] = *(const float4*)(skT + (16 + c16) * TSF + sl);
        *(float4*)&a1[4] = *(const float4*)(skT + (16 + c16) * TSF + sl + 4);
        const f16x8 Bh0 = *(const f16x8*)(svhiT + c16 * TSH + sl);
        const f16x8 Bh1 = *(const f16x8*)(svhiT + (16 + c16) * TSH + sl);
        const f16x8 Bl0 = *(const f16x8*)(svloT + c16 * TSH + sl);
        const f16x8 Bl1 = *(const f16x8*)(svloT + (16 + c16) * TSH + sl);

#pragma unroll
        for (int i = 0; i < 4; ++i) {
            const int o = w + 4 * i;
            const int r0 = ((c16 + o) & 31) * TSF;
            const int r1 = ((16 + c16 + o) & 31) * TSF;
            float e0[8], e1[8], p0[8], p1[8];
            *(float4*)&e0[0] = *(const float4*)(skT + r0 + sl);
            *(float4*)&e0[4] = *(const float4*)(skT + r0 + sl + 4);
            *(float4*)&e1[0] = *(const float4*)(skT + r1 + sl);
            *(float4*)&e1[4] = *(const float4*)(skT + r1 + sl + 4);
#pragma unroll
            for (int j = 0; j < 8; ++j) { p0[j] = a0[j] * e0[j]; p1[j] = a1[j] * e1[j]; }
            f16x8 A0h, A0l, A1h, A1l;
            split8(p0, A0h, A0l);
            split8(p1, A1h, A1l);
            acc[i][0][0] = MF(A0h, Bh0, acc[i][0][0]);
            acc[i][0][0] = MF(A0l, Bh0, acc[i][0][0]);
            acc[i][0][0] = MF(A0h, Bl0, acc[i][0][0]);
            acc[i][0][1] = MF(A0h, Bh1, acc[i][0][1]);
            acc[i][0][1] = MF(A0l, Bh1, acc[i][0][1]);
            acc[i][0][1] = MF(A0h, Bl1, acc[i][0][1]);
            acc[i][1][0] = MF(A1h, Bh0, acc[i][1][0]);
            acc[i][1][0] = MF(A1l, Bh0, acc[i][1][0]);
            acc[i][1][0] = MF(A1h, Bl0, acc[i][1][0]);
            acc[i][1][1] = MF(A1h, Bh1, acc[i][1][1]);
            acc[i][1][1] = MF(A1l, Bh1, acc[i][1][1]);
            acc[i][1][1] = MF(A1h, Bl1, acc[i][1][1]);
        }

        if (w == 0) {            // o=16 (duplicate-symmetric pair rows)
            float p[8];
#pragma unroll
            for (int j = 0; j < 8; ++j) p[j] = a0[j] * a1[j];
            f16x8 Ah, Al;
            split8(p, Ah, Al);
            accS[0][0] = MF(Ah, Bh0, accS[0][0]);
            accS[0][0] = MF(Al, Bh0, accS[0][0]);
            accS[0][0] = MF(Ah, Bl0, accS[0][0]);
            accS[0][1] = MF(Ah, Bh1, accS[0][1]);
            accS[0][1] = MF(Al, Bh1, accS[0][1]);
            accS[0][1] = MF(Ah, Bl1, accS[0][1]);
        } else if (w == 1) {     // kv1: A = k (split)
            f16x8 K0h, K0l, K1h, K1l;
            split8(a0, K0h, K0l);
            split8(a1, K1h, K1l);
            accS[0][0] = MF(K0h, Bh0, accS[0][0]);
            accS[0][0] = MF(K0l, Bh0, accS[0][0]);
            accS[0][0] = MF(K0h, Bl0, accS[0][0]);
            accS[0][1] = MF(K0h, Bh1, accS[0][1]);
            accS[0][1] = MF(K0l, Bh1, accS[0][1]);
            accS[0][1] = MF(K0h, Bl1, accS[0][1]);
            accS[1][0] = MF(K1h, Bh0, accS[1][0]);
            accS[1][0] = MF(K1l, Bh0, accS[1][0]);
            accS[1][0] = MF(K1h, Bl0, accS[1][0]);
            accS[1][1] = MF(K1h, Bh1, accS[1][1]);
            accS[1][1] = MF(K1l, Bh1, accS[1][1]);
            accS[1][1] = MF(K1h, Bl1, accS[1][1]);
        } else if (w == 2) {     // ksum: A = ones, B = k (split)
            f16x8 K0h, K0l, K1h, K1l;
            split8(a0, K0h, K0l);
            split8(a1, K1h, K1l);
            accS[0][0] = MF(ones, K0h, accS[0][0]);
            accS[0][0] = MF(ones, K0l, accS[0][0]);
            accS[1][0] = MF(ones, K1h, accS[1][0]);
            accS[1][0] = MF(ones, K1l, accS[1][0]);
        } else {                 // vsum: A = ones, B = v hi/lo
            accS[0][0] = MF(ones, Bh0, accS[0][0]);
            accS[0][0] = MF(ones, Bl0, accS[0][0]);
            accS[0][1] = MF(ones, Bh1, accS[0][1]);
            accS[0][1] = MF(ones, Bl1, accS[0][1]);
        }
    }

    // ---- store partials to slot (1+chunk) ----
    float* pb = ws + (size_t)SLOT1 * (1 + chunk) + (size_t)bh * BHF1;
#pragma unroll
    for (int i = 0; i < 4; ++i) {
        const int o = w + 4 * i;
#pragma unroll
        for (int m = 0; m < 2; ++m)
#pragma unroll
            for (int fh = 0; fh < 2; ++fh)
#pragma unroll
                for (int r = 0; r < 4; ++r) {
                    const int R = o * 32 + 16 * m + 4 * g + r;
                    pb[(size_t)R * 32 + fh * 16 + c16] = acc[i][m][fh][r];
                }
    }
    if (w == 0) {
#pragma unroll
        for (int fh = 0; fh < 2; ++fh)
#pragma unroll
            for (int r = 0; r < 4; ++r) {
                const int R = 512 + 4 * g + r;
                pb[(size_t)R * 32 + fh * 16 + c16] = accS[0][fh][r];
                pb[(size_t)(R + 16) * 32 + fh * 16 + c16] = accS[0][fh][r];
            }
    } else if (w == 1) {
#pragma unroll
        for (int m = 0; m < 2; ++m)
#pragma unroll
            for (int fh = 0; fh < 2; ++fh)
#pragma unroll
                for (int r = 0; r < 4; ++r) {
                    const int R = 544 + 16 * m + 4 * g + r;
                    pb[(size_t)R * 32 + fh * 16 + c16] = accS[m][fh][r];
                }
    } else if (w == 2) {
        if (g == 0) {
            pb[SUMOFF1 + c16] = accS[0][0][0];
            pb[SUMOFF1 + 16 + c16] = accS[1][0][0];
        }
    } else {
        if (g == 0) {
            pb[SUMOFF1 + 32 + c16] = accS[0][0][0];
            pb[SUMOFF1 + 48 + c16] = accS[0][1][0];
        }
    }
}

// ============ reduce (16 slots) + prep (f16 hi/lo B-frag pack) + sums ============
__global__ __launch_bounds__(256) void reduceprep_kernel(const float* __restrict__ ws,
                                                         float* __restrict__ wsw,
                                                         unsigned* __restrict__ bpk) {
    const int tid = blockIdx.x * 256 + threadIdx.x;
    if (tid < PK_HALF) {
        const int r = tid & 3;
        const int l = (tid >> 2) & 63;
        const int fh = (tid >> 8) & 1;
        const int kcbh = tid >> 9;
        const int kc = kcbh % KCH;
        const int bh = kcbh / KCH;
        const int f = fh * 16 + (l & 15);
        const int k0 = kc * 32 + ((l >> 4) << 3) + 2 * r;
        const float scale = (kc == 0 || kc == 16) ? 0.5f : 1.0f;
        float va = 0.f, vb = 0.f;
        const float* src = ws + (size_t)bh * BHF1 + (size_t)k0 * 32 + f;
#pragma unroll
        for (int c = 1; c <= KCH1; ++c) {
            va += src[(size_t)SLOT1 * c];
            vb += src[(size_t)SLOT1 * c + 32];
        }
        va *= scale; vb *= scale;
        const _Float16 ha = (_Float16)va, hb = (_Float16)vb;
        const _Float16 la = (_Float16)(va - (float)ha), lb = (_Float16)(vb - (float)hb);
        const int widx = ((bh * KCH + kc) * 2 + fh) * 512 + l * 4 + r;
        bpk[widx] = (unsigned)__builtin_bit_cast(unsigned short, ha) |
                    ((unsigned)__builtin_bit_cast(unsigned short, hb) << 16);
        bpk[widx + 256] = (unsigned)__builtin_bit_cast(unsigned short, la) |
                          ((unsigned)__builtin_bit_cast(unsigned short, lb) << 16);
    } else {
        const int tid2 = tid - PK_HALF;
        if (tid2 < NBH * 64) {
            const int bh = tid2 >> 6;
            const int j = tid2 & 63;
            float s = 0.f;
            const float* src = ws + (size_t)bh * BHF1 + SUMOFF1 + j;
#pragma unroll
            for (int c = 1; c <= KCH1; ++c) s += src[(size_t)SLOT1 * c];
            wsw[(size_t)bh * BHF1 + SUMOFF1 + j] = s;
        }
    }
}

// =================== phase 2: y = Phi * W via f16 MFMA (A single, B hi/lo) ===================
#define EMIT_PHI() do { \
    unsigned hh[16]; \
    _Pragma("unroll") \
    for (int kp = 0; kp < 16; ++kp) { \
        const _Float16 h0 = (_Float16)phi[2 * kp]; \
        const _Float16 h1 = (_Float16)phi[2 * kp + 1]; \
        hh[kp] = (unsigned)__builtin_bit_cast(unsigned short, h0) | \
                 ((unsigned)__builtin_bit_cast(unsigned short, h1) << 16); \
    } \
    _Pragma("unroll") \
    for (int c4 = 0; c4 < 4; ++c4) { \
        u32x4 vh = {hh[4*c4], hh[4*c4+1], hh[4*c4+2], hh[4*c4+3]}; \
        *(u32x4*)&sph[t * 20 + c4 * 4] = vh; \
    } \
} while (0)

#define MFMA_CHUNK(KC) do { \
    const unsigned* bc = bbase + (size_t)(KC) * 1024; \
    const f16x8 Bh0 = __builtin_bit_cast(f16x8, *(const u32x4*)(bc + 0   + l * 4)); \
    const f16x8 Bl0 = __builtin_bit_cast(f16x8, *(const u32x4*)(bc + 256 + l * 4)); \
    const f16x8 Bh1 = __builtin_bit_cast(f16x8, *(const u32x4*)(bc + 512 + l * 4)); \
    const f16x8 Bl1 = __builtin_bit_cast(f16x8, *(const u32x4*)(bc + 768 + l * 4)); \
    _Pragma("unroll") \
    for (int T = 0; T < 4; ++T) { \
        const int ro = (wbase + T * 16 + arow) * 20 + acol; \
        const f16x8 Ah = __builtin_bit_cast(f16x8, *(const u32x4*)&sph[ro]); \
        acc[T][0] = MF(Ah, Bh0, acc[T][0]); \
        acc[T][0] = MF(Ah, Bl0, acc[T][0]); \
        acc[T][1] = MF(Ah, Bh1, acc[T][1]); \
        acc[T][1] = MF(Ah, Bl1, acc[T][1]); \
    } \
} while (0)

__global__ __launch_bounds__(P2TOK) void phase2m_kernel(const float* __restrict__ qkv,
                                                        const float* __restrict__ ws,
                                                        const unsigned* __restrict__ bpk,
                                                        float* __restrict__ out) {
    const int bh = blockIdx.y;
    const int tok0 = blockIdx.x * P2TOK;
    const int t = threadIdx.x;
    const int l = t & 63;
    const int wbase = (t >> 6) << 6;
    const int arow = l & 15;
    const int acol = (l >> 4) << 2;

    __shared__ unsigned sph[P2TOK * 20];
    __shared__ float sinv[P2TOK];

    float q[32];
    {
        const float4* q4 = (const float4*)(qkv + ((size_t)bh * NTOK + tok0 + t) * DIM);
#pragma unroll
        for (int i = 0; i < 8; ++i) {
            const float4 v = q4[i];
            q[4 * i + 0] = v.x; q[4 * i + 1] = v.y; q[4 * i + 2] = v.z; q[4 * i + 3] = v.w;
        }
    }
    {
        const float* ks = ws + (size_t)bh * BHF1 + SUMOFF1;
        float qk = 0.f;
#pragma unroll
        for (int d = 0; d < 32; ++d) qk += q[d] * ks[d];
        sinv[t] = 1.0f / (0.5f * qk * qk + qk + 1.0f);
    }

    f32x4 acc[4][2];
#pragma unroll
    for (int T = 0; T < 4; ++T)
#pragma unroll
        for (int fh = 0; fh < 2; ++fh) acc[T][fh] = (f32x4){0.f, 0.f, 0.f, 0.f};

    const unsigned* bbase = bpk + (size_t)bh * (KCH * 1024);

    // chunks 0..16: offset o = kc, phi_j = q_j * q_{(j+kc)&31}
    {
        float qr[32];
#pragma unroll
        for (int j2 = 0; j2 < 32; ++j2) qr[j2] = q[j2];
#pragma unroll 1
        for (int kc = 0; kc < 17; ++kc) {
            float phi[32];
#pragma unroll
            for (int j2 = 0; j2 < 32; ++j2) phi[j2] = q[j2] * qr[j2];
            EMIT_PHI();
            MFMA_CHUNK(kc);
            const float tmp = qr[0];
#pragma unroll
            for (int j2 = 0; j2 < 31; ++j2) qr[j2] = qr[j2 + 1];
            qr[31] = tmp;
        }
    }
    // chunk 17: kv1, phi = q
    {
        float phi[32];
#pragma unroll
        for (int j2 = 0; j2 < 32; ++j2) phi[j2] = q[j2];
        EMIT_PHI();
        MFMA_CHUNK(17);
    }

    const float* vs = ws + (size_t)bh * BHF1 + SUMOFF1 + 32;
    const float vs0 = vs[l & 15];
    const float vs1 = vs[16 + (l & 15)];
#pragma unroll
    for (int T = 0; T < 4; ++T) {
#pragma unroll
        for (int r = 0; r < 4; ++r) {
            const int row = wbase + T * 16 + ((l >> 4) << 2) + r;
            const float iv = sinv[row];
            float* op = out + ((size_t)bh * NTOK + tok0 + row) * DIM + (l & 15);
            op[0]  = (acc[T][0][r] + vs0) * iv;
            op[16] = (acc[T][1][r] + vs1) * iv;
        }
    }
}

// =================== OLD fallback path (proven) ===================
__global__ __launch_bounds__(P1T) void phase1_kernel(const float* __restrict__ qkv,
                                                     float* __restrict__ ws, int direct) {
    const int chunk = blockIdx.x;
    const int bh = blockIdx.y;
    const int CHt = NTOK / gridDim.x;
    const int t = threadIdx.x;
    const float* kptr = qkv + (size_t)(NBH + bh) * (NTOK * DIM);
    const float* vptr = qkv + (size_t)(2 * NBH + bh) * (NTOK * DIM);
    float* base = ws + (direct ? (size_t)0 : (size_t)SLOT * (1 + chunk)) + (size_t)bh * BHF;

    __shared__ __align__(16) float sk[TILE][LSTR];
    __shared__ __align__(16) float sv[TILE][LSTR];

    int ia0, ib0, ia1, ib1;
    row_operands(t, ia0, ib0);
    row_operands(t + P1T, ia1, ib1);
    const float* a0 = &sk[0][ia0];
    const float* b0 = &sk[0][ib0];
    const float* a1 = &sk[0][ia1];
    const float* b1 = &sk[0][ib1];
    const float* sums = (t >= 288) ? &sv[0][t - 288] : ((t >= 256) ? &sk[0][t - 256] : &sk[0][0]);

    float acc0[32], acc1[32];
#pragma unroll
    for (int f = 0; f < 32; ++f) { acc0[f] = 0.f; acc1[f] = 0.f; }
    float accs = 0.f;

    if (t < 64) sk[t][32] = 1.0f;
    else if (t < 128) sk[t - 64][34] = 0.0f;

    const int n0 = chunk * CHt;
    for (int nt = 0; nt < CHt; nt += TILE) {
        __syncthreads();
        if (t < 256) {
            const float4* kg4 = (const float4*)(kptr + (size_t)(n0 + nt) * DIM);
            const float4* vg4 = (const float4*)(vptr + (size_t)(n0 + nt) * DIM);
            const int i0 = t, i1 = t + 256;
            *(float4*)&sk[i0 >> 3][(i0 & 7) << 2] = kg4[i0];
            *(float4*)&sk[i1 >> 3][(i1 & 7) << 2] = kg4[i1];
            *(float4*)&sv[i0 >> 3][(i0 & 7) << 2] = vg4[i0];
            *(float4*)&sv[i1 >> 3][(i1 & 7) << 2] = vg4[i1];
        }
        __syncthreads();
#pragma unroll 2
        for (int nn = 0; nn < TILE; ++nn) {
            const float s0 = a0[nn * LSTR] * b0[nn * LSTR];
            const float s1 = a1[nn * LSTR] * b1[nn * LSTR];
            const float* vrow = vptr + (size_t)(n0 + nt + nn) * DIM;
            float4 w[8];
#pragma unroll
            for (int j = 0; j < 8; ++j) w[j] = ((const float4*)vrow)[j];
#pragma unroll
            for (int j = 0; j < 8; ++j) {
                acc0[4 * j + 0] += s0 * w[j].x; acc0[4 * j + 1] += s0 * w[j].y;
                acc0[4 * j + 2] += s0 * w[j].z; acc0[4 * j + 3] += s0 * w[j].w;
                acc1[4 * j + 0] += s1 * w[j].x; acc1[4 * j + 1] += s1 * w[j].y;
                acc1[4 * j + 2] += s1 * w[j].z; acc1[4 * j + 3] += s1 * w[j].w;
            }
            if (t >= 256) accs += sums[nn * LSTR];
        }
    }

    {
        float* dst = base + (size_t)t * 32;
#pragma unroll
        for (int j = 0; j < 8; ++j) {
            float4 v; v.x = acc0[4 * j]; v.y = acc0[4 * j + 1];
            v.z = acc0[4 * j + 2]; v.w = acc0[4 * j + 3];
            ((float4*)dst)[j] = v;
        }
    }
    if (t < 240) {
        float* dst = base + (size_t)(t + P1T) * 32;
#pragma unroll
        for (int j = 0; j < 8; ++j) {
            float4 v; v.x = acc1[4 * j]; v.y = acc1[4 * j + 1];
            v.z = acc1[4 * j + 2]; v.w = acc1[4 * j + 3];
            ((float4*)dst)[j] = v;
        }
    }
    if (t >= 256) base[NROWS * 32 + (t - 256)] = accs;
}

__global__ __launch_bounds__(256) void phase2_kernel(const float* __restrict__ qkv,
                                                     const float* __restrict__ ws,
                                                     float* __restrict__ out) {
    const int bh = blockIdx.y;
    const int f0 = blockIdx.z << 4;
    const int t = threadIdx.x;
    const int tok0 = blockIdx.x * 256;
    const float* qptr = qkv + (size_t)bh * (NTOK * DIM) + (size_t)tok0 * DIM;
    const float* base = ws + (size_t)bh * BHF;
    const float* ksum = base + NROWS * 32;
    const float* vsum = ksum + 32;

    __shared__ float qT[32][256];
    {
        const float4* q4 = (const float4*)qptr + (size_t)t * 8;
#pragma unroll
        for (int i = 0; i < 8; ++i) {
            const float4 v = q4[i];
            qT[4 * i + 0][t] = v.x; qT[4 * i + 1][t] = v.y;
            qT[4 * i + 2][t] = v.z; qT[4 * i + 3][t] = v.w;
        }
    }
    __syncthreads();

    float y[16];
#pragma unroll
    for (int j = 0; j < 4; ++j) {
        const float4 v = *(const float4*)(vsum + f0 + 4 * j);
        y[4 * j + 0] = v.x; y[4 * j + 1] = v.y; y[4 * j + 2] = v.z; y[4 * j + 3] = v.w;
    }
    float qk = 0.f;
    const float* rowp = base + f0;
#pragma unroll 1
    for (int d = 0; d < 32; ++d) {
        const float qd = qT[d][t];
        qk += qd * ksum[d];
        {
            const float s = 0.5f * qd * qd;
            const float4* r = (const float4*)rowp;
#pragma unroll
            for (int j = 0; j < 4; ++j) {
                const float4 w = r[j];
                y[4 * j + 0] += s * w.x; y[4 * j + 1] += s * w.y;
                y[4 * j + 2] += s * w.z; y[4 * j + 3] += s * w.w;
            }
            rowp += 32;
        }
#pragma unroll 4
        for (int e = d + 1; e < 32; ++e) {
            const float s = qd * qT[e][t];
            const float4* r = (const float4*)rowp;
#pragma unroll
            for (int j = 0; j < 4; ++j) {
                const float4 w = r[j];
                y[4 * j + 0] += s * w.x; y[4 * j + 1] += s * w.y;
                y[4 * j + 2] += s * w.z; y[4 * j + 3] += s * w.w;
            }
            rowp += 32;
        }
    }
#pragma unroll 4
    for (int d = 0; d < 32; ++d) {
        const float qd = qT[d][t];
        const float4* r = (const float4*)rowp;
#pragma unroll
        for (int j = 0; j < 4; ++j) {
            const float4 w = r[j];
            y[4 * j + 0] += qd * w.x; y[4 * j + 1] += qd * w.y;
            y[4 * j + 2] += qd * w.z; y[4 * j + 3] += qd * w.w;
        }
        rowp += 32;
    }
    const float inv = 1.0f / (0.5f * qk * qk + qk + 1.0f);
    float4* o4 = (float4*)(out + (size_t)bh * (NTOK * DIM) + (size_t)(tok0 + t) * DIM + f0);
#pragma unroll
    for (int j = 0; j < 4; ++j) {
        float4 v;
        v.x = y[4 * j + 0] * inv; v.y = y[4 * j + 1] * inv;
        v.z = y[4 * j + 2] * inv; v.w = y[4 * j + 3] * inv;
        o4[j] = v;
    }
}

extern "C" void kernel_launch(void* const* d_in, const int* in_sizes, int n_in,
                              void* d_out, int out_size, void* d_ws, size_t ws_size,
                              hipStream_t stream) {
    const float* qkv = (const float*)d_in[0];
    float* out = (float*)d_out;
    float* ws = (float*)d_ws;

    const size_t need = ((size_t)(1 + KCH1) * SLOT1 + PK_U32) * 4;
    if (ws_size >= need) {
        unsigned* bpk = (unsigned*)(ws + (size_t)(1 + KCH1) * SLOT1);
        phase1m_kernel<<<dim3(KCH1, NBH), dim3(256), 0, stream>>>(qkv, ws);
        reduceprep_kernel<<<dim3((PK_HALF + NBH * 64) / 256), dim3(256), 0, stream>>>(ws, ws, bpk);
        phase2m_kernel<<<dim3(NTOK / P2TOK, NBH), dim3(P2TOK), 0, stream>>>(qkv, ws, bpk, out);
    } else {
        phase1_kernel<<<dim3(1, NBH), dim3(P1T), 0, stream>>>(qkv, ws, 1);
        phase2_kernel<<<dim3(NTOK / 256, NBH, 2), dim3(256), 0, stream>>>(qkv, ws, out);
    }
}

// Round 11
// 62.384 us; speedup vs baseline: 2.8688x; 1.0072x over previous
//
#include <hip/hip_runtime.h>

#define NTOK 4096
#define DIM 32
#define NBH 32              // B*H

// ---------- MFMA phase1 layout ----------
#define BHF1 18496          // 576 rows * 32 f + 64 sums
#define SLOT1 591872        // NBH * BHF1 floats (2.37 MB)
#define SUMOFF1 18432       // 576*32
#define KCH1 16             // phase1 token chunks (256 tok each)
#define TSF 260             // skT token stride in fp32 (1040 B, 16B-aligned)
#define TSH 264             // svT token stride in fp16 (528 B, 16B-aligned)

#define KCH 18              // phase2 K-chunks (K = 576)
#define PK_U32 (NBH * KCH * 1024)   // 589,824 packed B-frag u32
#define PK_HALF (PK_U32 / 2)        // 294,912
#define P2TOK 64            // 1 wave per block

// ---------- OLD (fallback) layout ----------
#define NPAIR2 528
#define NROWS 560
#define BHF (NROWS * 32 + 64)       // 17984
#define SLOT (NBH * BHF)            // 575488
#define TILE 64
#define LSTR 36
#define P1T 320

typedef __attribute__((ext_vector_type(8))) short bf16x8;
typedef __attribute__((ext_vector_type(8))) _Float16 f16x8;
typedef __attribute__((ext_vector_type(4))) float f32x4;
typedef __attribute__((ext_vector_type(4))) unsigned u32x4;

__device__ __forceinline__ int tri_start(int d) { return (d * (65 - d)) >> 1; }

__device__ __forceinline__ int tri_decode_d(int p) {
    int d = (int)((65.0f - sqrtf((float)(4225 - 8 * p))) * 0.5f);
    if (d < 0) d = 0;
    if (d > 31) d = 31;
    while (d < 31 && tri_start(d + 1) <= p) ++d;
    while (d > 0 && tri_start(d) > p) --d;
    return d;
}

__device__ __forceinline__ void row_operands(int row, int& ia, int& ib) {
    if (row < NPAIR2) {
        const int d = tri_decode_d(row);
        ia = d; ib = d + (row - tri_start(d));
    } else if (row < NROWS) {
        ia = row - NPAIR2; ib = 32;
    } else {
        ia = 34; ib = 34;
    }
}

// fp32[8] -> f16 hi/lo fragments (hi = RTN, lo = exact residual)
__device__ __forceinline__ void split8(const float* p, f16x8& hi, f16x8& lo) {
#pragma unroll
    for (int j = 0; j < 8; ++j) {
        const _Float16 h = (_Float16)p[j];
        hi[j] = h;
        lo[j] = (_Float16)(p[j] - (float)h);
    }
}

#define MF(A, B, C) __builtin_amdgcn_mfma_f32_16x16x32_f16((A), (B), (C), 0, 0, 0)

// =================== Phase 1 (MFMA, fp32-exact A-products) ===================
// W row R = o*32+d (o=0..16, pair (d,(d+o)&31)); R = 544+d: kv1. Sums at SUMOFF1.
// Wave w: offsets {w, w+4, w+8, w+12} + special (w0: o16, w1: kv1, w2: ksum, w3: vsum).
__global__ __launch_bounds__(256) void phase1m_kernel(const float* __restrict__ qkv,
                                                      float* __restrict__ ws) {
    const int chunk = blockIdx.x;
    const int bh = blockIdx.y;
    const int t = threadIdx.x;
    const int w = t >> 6, l = t & 63, g = l >> 4, c16 = l & 15;

    __shared__ float skT[32 * TSF];        // 33.3 KB
    __shared__ _Float16 svhiT[32 * TSH];   // 16.9 KB
    __shared__ _Float16 svloT[32 * TSH];   // 16.9 KB

    // ---- stage 256 tokens: k fp32 transposed, v f16 hi/lo transposed ----
    {
        const float4* kg4 = (const float4*)(qkv + (size_t)(NBH + bh) * (NTOK * DIM) + (size_t)chunk * 256 * DIM);
        const float4* vg4 = (const float4*)(qkv + (size_t)(2 * NBH + bh) * (NTOK * DIM) + (size_t)chunk * 256 * DIM);
#pragma unroll
        for (int j = 0; j < 8; ++j) {
            const int i = t + 256 * j;
            const int tok = i >> 3, dbase = (i & 7) << 2;
            const float4 kf = kg4[i];
            const float4 vf = vg4[i];
            const float ke[4] = {kf.x, kf.y, kf.z, kf.w};
            const float ve[4] = {vf.x, vf.y, vf.z, vf.w};
#pragma unroll
            for (int c = 0; c < 4; ++c) {
                skT[(dbase + c) * TSF + tok] = ke[c];
                const _Float16 h = (_Float16)ve[c];
                svhiT[(dbase + c) * TSH + tok] = h;
                svloT[(dbase + c) * TSH + tok] = (_Float16)(ve[c] - (float)h);
            }
        }
    }
    __syncthreads();

    f32x4 acc[4][2][2];
    f32x4 accS[2][2];
#pragma unroll
    for (int i = 0; i < 4; ++i)
#pragma unroll
        for (int m = 0; m < 2; ++m)
#pragma unroll
            for (int fh = 0; fh < 2; ++fh) acc[i][m][fh] = (f32x4){0.f, 0.f, 0.f, 0.f};
#pragma unroll
    for (int m = 0; m < 2; ++m)
#pragma unroll
        for (int fh = 0; fh < 2; ++fh) accS[m][fh] = (f32x4){0.f, 0.f, 0.f, 0.f};

    const f16x8 ones = {(_Float16)1.f, (_Float16)1.f, (_Float16)1.f, (_Float16)1.f,
                        (_Float16)1.f, (_Float16)1.f, (_Float16)1.f, (_Float16)1.f};

#pragma unroll 1
    for (int n0 = 0; n0 < 256; n0 += 32) {
        const int sl = n0 + 8 * g;
        float a0[8], a1[8];
        *(float4*)&a0[0] = *(const float4*)(skT + c16 * TSF + sl);
        *(float4*)&a0[4] = *(const float4*)(skT + c16 * TSF + sl + 4);
        *(float4*)&a1[0] = *(const float4*)(skT + (16 + c16) * TSF + sl);
        *(float4*)&a1[4] = *(const float4*)(skT + (16 + c16) * TSF + sl + 4);
        const f16x8 Bh0 = *(const f16x8*)(svhiT + c16 * TSH + sl);
        const f16x8 Bh1 = *(const f16x8*)(svhiT + (16 + c16) * TSH + sl);
        const f16x8 Bl0 = *(const f16x8*)(svloT + c16 * TSH + sl);
        const f16x8 Bl1 = *(const f16x8*)(svloT + (16 + c16) * TSH + sl);

#pragma unroll
        for (int i = 0; i < 4; ++i) {
            const int o = w + 4 * i;
            const int r0 = ((c16 + o) & 31) * TSF;
            const int r1 = ((16 + c16 + o) & 31) * TSF;
            float e0[8], e1[8], p0[8], p1[8];
            *(float4*)&e0[0] = *(const float4*)(skT + r0 + sl);
            *(float4*)&e0[4] = *(const float4*)(skT + r0 + sl + 4);
            *(float4*)&e1[0] = *(const float4*)(skT + r1 + sl);
            *(float4*)&e1[4] = *(const float4*)(skT + r1 + sl + 4);
#pragma unroll
            for (int j = 0; j < 8; ++j) { p0[j] = a0[j] * e0[j]; p1[j] = a1[j] * e1[j]; }
            f16x8 A0h, A0l, A1h, A1l;
            split8(p0, A0h, A0l);
            split8(p1, A1h, A1l);
            acc[i][0][0] = MF(A0h, Bh0, acc[i][0][0]);
            acc[i][0][0] = MF(A0l, Bh0, acc[i][0][0]);
            acc[i][0][0] = MF(A0h, Bl0, acc[i][0][0]);
            acc[i][0][1] = MF(A0h, Bh1, acc[i][0][1]);
            acc[i][0][1] = MF(A0l, Bh1, acc[i][0][1]);
            acc[i][0][1] = MF(A0h, Bl1, acc[i][0][1]);
            acc[i][1][0] = MF(A1h, Bh0, acc[i][1][0]);
            acc[i][1][0] = MF(A1l, Bh0, acc[i][1][0]);
            acc[i][1][0] = MF(A1h, Bl0, acc[i][1][0]);
            acc[i][1][1] = MF(A1h, Bh1, acc[i][1][1]);
            acc[i][1][1] = MF(A1l, Bh1, acc[i][1][1]);
            acc[i][1][1] = MF(A1h, Bl1, acc[i][1][1]);
        }

        if (w == 0) {            // o=16 (duplicate-symmetric pair rows)
            float p[8];
#pragma unroll
            for (int j = 0; j < 8; ++j) p[j] = a0[j] * a1[j];
            f16x8 Ah, Al;
            split8(p, Ah, Al);
            accS[0][0] = MF(Ah, Bh0, accS[0][0]);
            accS[0][0] = MF(Al, Bh0, accS[0][0]);
            accS[0][0] = MF(Ah, Bl0, accS[0][0]);
            accS[0][1] = MF(Ah, Bh1, accS[0][1]);
            accS[0][1] = MF(Al, Bh1, accS[0][1]);
            accS[0][1] = MF(Ah, Bl1, accS[0][1]);
        } else if (w == 1) {     // kv1: A = k (split)
            f16x8 K0h, K0l, K1h, K1l;
            split8(a0, K0h, K0l);
            split8(a1, K1h, K1l);
            accS[0][0] = MF(K0h, Bh0, accS[0][0]);
            accS[0][0] = MF(K0l, Bh0, accS[0][0]);
            accS[0][0] = MF(K0h, Bl0, accS[0][0]);
            accS[0][1] = MF(K0h, Bh1, accS[0][1]);
            accS[0][1] = MF(K0l, Bh1, accS[0][1]);
            accS[0][1] = MF(K0h, Bl1, accS[0][1]);
            accS[1][0] = MF(K1h, Bh0, accS[1][0]);
            accS[1][0] = MF(K1l, Bh0, accS[1][0]);
            accS[1][0] = MF(K1h, Bl0, accS[1][0]);
            accS[1][1] = MF(K1h, Bh1, accS[1][1]);
            accS[1][1] = MF(K1l, Bh1, accS[1][1]);
            accS[1][1] = MF(K1h, Bl1, accS[1][1]);
        } else if (w == 2) {     // ksum: A = ones, B = k (split)
            f16x8 K0h, K0l, K1h, K1l;
            split8(a0, K0h, K0l);
            split8(a1, K1h, K1l);
            accS[0][0] = MF(ones, K0h, accS[0][0]);
            accS[0][0] = MF(ones, K0l, accS[0][0]);
            accS[1][0] = MF(ones, K1h, accS[1][0]);
            accS[1][0] = MF(ones, K1l, accS[1][0]);
        } else {                 // vsum: A = ones, B = v hi/lo
            accS[0][0] = MF(ones, Bh0, accS[0][0]);
            accS[0][0] = MF(ones, Bl0, accS[0][0]);
            accS[0][1] = MF(ones, Bh1, accS[0][1]);
            accS[0][1] = MF(ones, Bl1, accS[0][1]);
        }
    }

    // ---- store partials to slot (1+chunk) ----
    float* pb = ws + (size_t)SLOT1 * (1 + chunk) + (size_t)bh * BHF1;
#pragma unroll
    for (int i = 0; i < 4; ++i) {
        const int o = w + 4 * i;
#pragma unroll
        for (int m = 0; m < 2; ++m)
#pragma unroll
            for (int fh = 0; fh < 2; ++fh)
#pragma unroll
                for (int r = 0; r < 4; ++r) {
                    const int R = o * 32 + 16 * m + 4 * g + r;
                    pb[(size_t)R * 32 + fh * 16 + c16] = acc[i][m][fh][r];
                }
    }
    if (w == 0) {
#pragma unroll
        for (int fh = 0; fh < 2; ++fh)
#pragma unroll
            for (int r = 0; r < 4; ++r) {
                const int R = 512 + 4 * g + r;
                pb[(size_t)R * 32 + fh * 16 + c16] = accS[0][fh][r];
                pb[(size_t)(R + 16) * 32 + fh * 16 + c16] = accS[0][fh][r];
            }
    } else if (w == 1) {
#pragma unroll
        for (int m = 0; m < 2; ++m)
#pragma unroll
            for (int fh = 0; fh < 2; ++fh)
#pragma unroll
                for (int r = 0; r < 4; ++r) {
                    const int R = 544 + 16 * m + 4 * g + r;
                    pb[(size_t)R * 32 + fh * 16 + c16] = accS[m][fh][r];
                }
    } else if (w == 2) {
        if (g == 0) {
            pb[SUMOFF1 + c16] = accS[0][0][0];
            pb[SUMOFF1 + 16 + c16] = accS[1][0][0];
        }
    } else {
        if (g == 0) {
            pb[SUMOFF1 + 32 + c16] = accS[0][0][0];
            pb[SUMOFF1 + 48 + c16] = accS[0][1][0];
        }
    }
}

// ============ reduce (16 slots) + prep (f16 hi/lo B-frag pack) + sums ============
__global__ __launch_bounds__(256) void reduceprep_kernel(const float* __restrict__ ws,
                                                         float* __restrict__ wsw,
                                                         unsigned* __restrict__ bpk) {
    const int tid = blockIdx.x * 256 + threadIdx.x;
    if (tid < PK_HALF) {
        const int r = tid & 3;
        const int l = (tid >> 2) & 63;
        const int fh = (tid >> 8) & 1;
        const int kcbh = tid >> 9;
        const int kc = kcbh % KCH;
        const int bh = kcbh / KCH;
        const int f = fh * 16 + (l & 15);
        const int k0 = kc * 32 + ((l >> 4) << 3) + 2 * r;
        const float scale = (kc == 0 || kc == 16) ? 0.5f : 1.0f;
        float va = 0.f, vb = 0.f;
        const float* src = ws + (size_t)bh * BHF1 + (size_t)k0 * 32 + f;
#pragma unroll
        for (int c = 1; c <= KCH1; ++c) {
            va += src[(size_t)SLOT1 * c];
            vb += src[(size_t)SLOT1 * c + 32];
        }
        va *= scale; vb *= scale;
        const _Float16 ha = (_Float16)va, hb = (_Float16)vb;
        const _Float16 la = (_Float16)(va - (float)ha), lb = (_Float16)(vb - (float)hb);
        const int widx = ((bh * KCH + kc) * 2 + fh) * 512 + l * 4 + r;
        bpk[widx] = (unsigned)__builtin_bit_cast(unsigned short, ha) |
                    ((unsigned)__builtin_bit_cast(unsigned short, hb) << 16);
        bpk[widx + 256] = (unsigned)__builtin_bit_cast(unsigned short, la) |
                          ((unsigned)__builtin_bit_cast(unsigned short, lb) << 16);
    } else {
        const int tid2 = tid - PK_HALF;
        if (tid2 < NBH * 64) {
            const int bh = tid2 >> 6;
            const int j = tid2 & 63;
            float s = 0.f;
            const float* src = ws + (size_t)bh * BHF1 + SUMOFF1 + j;
#pragma unroll
            for (int c = 1; c <= KCH1; ++c) s += src[(size_t)SLOT1 * c];
            wsw[(size_t)bh * BHF1 + SUMOFF1 + j] = s;
        }
    }
}

// ====== phase 2: y = Phi * W via f16 MFMA (A single, B hi/lo), fully unrolled ======
// 1 wave per block (64 tokens). Chunk kc<17: phi_j = q_j*q_{(j+kc)&31} (all static after
// unroll); kc=17: phi = q. No qr rotation, no barriers (per-wave LDS region, in-order DS).
__global__ __launch_bounds__(P2TOK) void phase2m_kernel(const float* __restrict__ qkv,
                                                        const float* __restrict__ ws,
                                                        const unsigned* __restrict__ bpk,
                                                        float* __restrict__ out) {
    const int bh = blockIdx.y;
    const int tok0 = blockIdx.x * P2TOK;
    const int t = threadIdx.x;          // 0..63 == lane
    const int arow = t & 15;
    const int acol = (t >> 4) << 2;

    __shared__ unsigned sph[P2TOK * 20];
    __shared__ float sinv[P2TOK];

    float q[32];
    {
        const float4* q4 = (const float4*)(qkv + ((size_t)bh * NTOK + tok0 + t) * DIM);
#pragma unroll
        for (int i = 0; i < 8; ++i) {
            const float4 v = q4[i];
            q[4 * i + 0] = v.x; q[4 * i + 1] = v.y; q[4 * i + 2] = v.z; q[4 * i + 3] = v.w;
        }
    }
    {
        const float* ks = ws + (size_t)bh * BHF1 + SUMOFF1;
        float qk = 0.f;
#pragma unroll
        for (int d = 0; d < 32; ++d) qk += q[d] * ks[d];
        sinv[t] = 1.0f / (0.5f * qk * qk + qk + 1.0f);
    }

    f32x4 acc[4][2];
#pragma unroll
    for (int T = 0; T < 4; ++T)
#pragma unroll
        for (int fh = 0; fh < 2; ++fh) acc[T][fh] = (f32x4){0.f, 0.f, 0.f, 0.f};

    const unsigned* bbase = bpk + (size_t)bh * (KCH * 1024);

#pragma unroll
    for (int kc = 0; kc < KCH; ++kc) {
        // ---- emit phi (static indices; RTN casts) ----
        unsigned hh[16];
#pragma unroll
        for (int kp = 0; kp < 16; ++kp) {
            const int j0 = 2 * kp, j1 = 2 * kp + 1;
            const float p0 = (kc < 17) ? q[j0] * q[(j0 + kc) & 31] : q[j0];
            const float p1 = (kc < 17) ? q[j1] * q[(j1 + kc) & 31] : q[j1];
            const _Float16 h0 = (_Float16)p0;
            const _Float16 h1 = (_Float16)p1;
            hh[kp] = (unsigned)__builtin_bit_cast(unsigned short, h0) |
                     ((unsigned)__builtin_bit_cast(unsigned short, h1) << 16);
        }
#pragma unroll
        for (int c4 = 0; c4 < 4; ++c4) {
            u32x4 vh = {hh[4 * c4], hh[4 * c4 + 1], hh[4 * c4 + 2], hh[4 * c4 + 3]};
            *(u32x4*)&sph[t * 20 + c4 * 4] = vh;
        }
        // ---- B frags + MFMA ----
        const unsigned* bc = bbase + (size_t)kc * 1024;
        const f16x8 Bh0 = __builtin_bit_cast(f16x8, *(const u32x4*)(bc + 0   + t * 4));
        const f16x8 Bl0 = __builtin_bit_cast(f16x8, *(const u32x4*)(bc + 256 + t * 4));
        const f16x8 Bh1 = __builtin_bit_cast(f16x8, *(const u32x4*)(bc + 512 + t * 4));
        const f16x8 Bl1 = __builtin_bit_cast(f16x8, *(const u32x4*)(bc + 768 + t * 4));
#pragma unroll
        for (int T = 0; T < 4; ++T) {
            const int ro = (T * 16 + arow) * 20 + acol;
            const f16x8 Ah = __builtin_bit_cast(f16x8, *(const u32x4*)&sph[ro]);
            acc[T][0] = MF(Ah, Bh0, acc[T][0]);
            acc[T][0] = MF(Ah, Bl0, acc[T][0]);
            acc[T][1] = MF(Ah, Bh1, acc[T][1]);
            acc[T][1] = MF(Ah, Bl1, acc[T][1]);
        }
    }

    const float* vs = ws + (size_t)bh * BHF1 + SUMOFF1 + 32;
    const float vs0 = vs[t & 15];
    const float vs1 = vs[16 + (t & 15)];
#pragma unroll
    for (int T = 0; T < 4; ++T) {
#pragma unroll
        for (int r = 0; r < 4; ++r) {
            const int row = T * 16 + ((t >> 4) << 2) + r;
            const float iv = sinv[row];
            float* op = out + ((size_t)bh * NTOK + tok0 + row) * DIM + (t & 15);
            op[0]  = (acc[T][0][r] + vs0) * iv;
            op[16] = (acc[T][1][r] + vs1) * iv;
        }
    }
}

// =================== OLD fallback path (proven) ===================
__global__ __launch_bounds__(P1T) void phase1_kernel(const float* __restrict__ qkv,
                                                     float* __restrict__ ws, int direct) {
    const int chunk = blockIdx.x;
    const int bh = blockIdx.y;
    const int CHt = NTOK / gridDim.x;
    const int t = threadIdx.x;
    const float* kptr = qkv + (size_t)(NBH + bh) * (NTOK * DIM);
    const float* vptr = qkv + (size_t)(2 * NBH + bh) * (NTOK * DIM);
    float* base = ws + (direct ? (size_t)0 : (size_t)SLOT * (1 + chunk)) + (size_t)bh * BHF;

    __shared__ __align__(16) float sk[TILE][LSTR];
    __shared__ __align__(16) float sv[TILE][LSTR];

    int ia0, ib0, ia1, ib1;
    row_operands(t, ia0, ib0);
    row_operands(t + P1T, ia1, ib1);
    const float* a0 = &sk[0][ia0];
    const float* b0 = &sk[0][ib0];
    const float* a1 = &sk[0][ia1];
    const float* b1 = &sk[0][ib1];
    const float* sums = (t >= 288) ? &sv[0][t - 288] : ((t >= 256) ? &sk[0][t - 256] : &sk[0][0]);

    float acc0[32], acc1[32];
#pragma unroll
    for (int f = 0; f < 32; ++f) { acc0[f] = 0.f; acc1[f] = 0.f; }
    float accs = 0.f;

    if (t < 64) sk[t][32] = 1.0f;
    else if (t < 128) sk[t - 64][34] = 0.0f;

    const int n0 = chunk * CHt;
    for (int nt = 0; nt < CHt; nt += TILE) {
        __syncthreads();
        if (t < 256) {
            const float4* kg4 = (const float4*)(kptr + (size_t)(n0 + nt) * DIM);
            const float4* vg4 = (const float4*)(vptr + (size_t)(n0 + nt) * DIM);
            const int i0 = t, i1 = t + 256;
            *(float4*)&sk[i0 >> 3][(i0 & 7) << 2] = kg4[i0];
            *(float4*)&sk[i1 >> 3][(i1 & 7) << 2] = kg4[i1];
            *(float4*)&sv[i0 >> 3][(i0 & 7) << 2] = vg4[i0];
            *(float4*)&sv[i1 >> 3][(i1 & 7) << 2] = vg4[i1];
        }
        __syncthreads();
#pragma unroll 2
        for (int nn = 0; nn < TILE; ++nn) {
            const float s0 = a0[nn * LSTR] * b0[nn * LSTR];
            const float s1 = a1[nn * LSTR] * b1[nn * LSTR];
            const float* vrow = vptr + (size_t)(n0 + nt + nn) * DIM;
            float4 w[8];
#pragma unroll
            for (int j = 0; j < 8; ++j) w[j] = ((const float4*)vrow)[j];
#pragma unroll
            for (int j = 0; j < 8; ++j) {
                acc0[4 * j + 0] += s0 * w[j].x; acc0[4 * j + 1] += s0 * w[j].y;
                acc0[4 * j + 2] += s0 * w[j].z; acc0[4 * j + 3] += s0 * w[j].w;
                acc1[4 * j + 0] += s1 * w[j].x; acc1[4 * j + 1] += s1 * w[j].y;
                acc1[4 * j + 2] += s1 * w[j].z; acc1[4 * j + 3] += s1 * w[j].w;
            }
            if (t >= 256) accs += sums[nn * LSTR];
        }
    }

    {
        float* dst = base + (size_t)t * 32;
#pragma unroll
        for (int j = 0; j < 8; ++j) {
            float4 v; v.x = acc0[4 * j]; v.y = acc0[4 * j + 1];
            v.z = acc0[4 * j + 2]; v.w = acc0[4 * j + 3];
            ((float4*)dst)[j] = v;
        }
    }
    if (t < 240) {
        float* dst = base + (size_t)(t + P1T) * 32;
#pragma unroll
        for (int j = 0; j < 8; ++j) {
            float4 v; v.x = acc1[4 * j]; v.y = acc1[4 * j + 1];
            v.z = acc1[4 * j + 2]; v.w = acc1[4 * j + 3];
            ((float4*)dst)[j] = v;
        }
    }
    if (t >= 256) base[NROWS * 32 + (t - 256)] = accs;
}

__global__ __launch_bounds__(256) void phase2_kernel(const float* __restrict__ qkv,
                                                     const float* __restrict__ ws,
                                                     float* __restrict__ out) {
    const int bh = blockIdx.y;
    const int f0 = blockIdx.z << 4;
    const int t = threadIdx.x;
    const int tok0 = blockIdx.x * 256;
    const float* qptr = qkv + (size_t)bh * (NTOK * DIM) + (size_t)tok0 * DIM;
    const float* base = ws + (size_t)bh * BHF;
    const float* ksum = base + NROWS * 32;
    const float* vsum = ksum + 32;

    __shared__ float qT[32][256];
    {
        const float4* q4 = (const float4*)qptr + (size_t)t * 8;
#pragma unroll
        for (int i = 0; i < 8; ++i) {
            const float4 v = q4[i];
            qT[4 * i + 0][t] = v.x; qT[4 * i + 1][t] = v.y;
            qT[4 * i + 2][t] = v.z; qT[4 * i + 3][t] = v.w;
        }
    }
    __syncthreads();

    float y[16];
#pragma unroll
    for (int j = 0; j < 4; ++j) {
        const float4 v = *(const float4*)(vsum + f0 + 4 * j);
        y[4 * j + 0] = v.x; y[4 * j + 1] = v.y; y[4 * j + 2] = v.z; y[4 * j + 3] = v.w;
    }
    float qk = 0.f;
    const float* rowp = base + f0;
#pragma unroll 1
    for (int d = 0; d < 32; ++d) {
        const float qd = qT[d][t];
        qk += qd * ksum[d];
        {
            const float s = 0.5f * qd * qd;
            const float4* r = (const float4*)rowp;
#pragma unroll
            for (int j = 0; j < 4; ++j) {
                const float4 w = r[j];
                y[4 * j + 0] += s * w.x; y[4 * j + 1] += s * w.y;
                y[4 * j + 2] += s * w.z; y[4 * j + 3] += s * w.w;
            }
            rowp += 32;
        }
#pragma unroll 4
        for (int e = d + 1; e < 32; ++e) {
            const float s = qd * qT[e][t];
            const float4* r = (const float4*)rowp;
#pragma unroll
            for (int j = 0; j < 4; ++j) {
                const float4 w = r[j];
                y[4 * j + 0] += s * w.x; y[4 * j + 1] += s * w.y;
                y[4 * j + 2] += s * w.z; y[4 * j + 3] += s * w.w;
            }
            rowp += 32;
        }
    }
#pragma unroll 4
    for (int d = 0; d < 32; ++d) {
        const float qd = qT[d][t];
        const float4* r = (const float4*)rowp;
#pragma unroll
        for (int j = 0; j < 4; ++j) {
            const float4 w = r[j];
            y[4 * j + 0] += qd * w.x; y[4 * j + 1] += qd * w.y;
            y[4 * j + 2] += qd * w.z; y[4 * j + 3] += qd * w.w;
        }
        rowp += 32;
    }
    const float inv = 1.0f / (0.5f * qk * qk + qk + 1.0f);
    float4* o4 = (float4*)(out + (size_t)bh * (NTOK * DIM) + (size_t)(tok0 + t) * DIM + f0);
#pragma unroll
    for (int j = 0; j < 4; ++j) {
        float4 v;
        v.x = y[4 * j + 0] * inv; v.y = y[4 * j + 1] * inv;
        v.z = y[4 * j + 2] * inv; v.w = y[4 * j + 3] * inv;
        o4[j] = v;
    }
}

extern "C" void kernel_launch(void* const* d_in, const int* in_sizes, int n_in,
                              void* d_out, int out_size, void* d_ws, size_t ws_size,
                              hipStream_t stream) {
    const float* qkv = (const float*)d_in[0];
    float* out = (float*)d_out;
    float* ws = (float*)d_ws;

    const size_t need = ((size_t)(1 + KCH1) * SLOT1 + PK_U32) * 4;
    if (ws_size >= need) {
        unsigned* bpk = (unsigned*)(ws + (size_t)(1 + KCH1) * SLOT1);
        phase1m_kernel<<<dim3(KCH1, NBH), dim3(256), 0, stream>>>(qkv, ws);
        reduceprep_kernel<<<dim3((PK_HALF + NBH * 64) / 256), dim3(256), 0, stream>>>(ws, ws, bpk);
        phase2m_kernel<<<dim3(NTOK / P2TOK, NBH), dim3(P2TOK), 0, stream>>>(qkv, ws, bpk, out);
    } else {
        phase1_kernel<<<dim3(1, NBH), dim3(P1T), 0, stream>>>(qkv, ws, 1);
        phase2_kernel<<<dim3(NTOK / 256, NBH, 2), dim3(256), 0, stream>>>(qkv, ws, out);
    }
}

// Round 12
// 61.361 us; speedup vs baseline: 2.9167x; 1.0167x over previous
//
#include <hip/hip_runtime.h>

#define NTOK 4096
#define DIM 32
#define NBH 32              // B*H

// ---------- MFMA phase1 layout ----------
#define BHF1 18496          // 576 rows * 32 f + 64 sums
#define SLOT1 591872        // NBH * BHF1 floats (2.37 MB)
#define SUMOFF1 18432       // 576*32
#define KCH1 16             // phase1 token chunks (256 tok each)
#define TSF2 132            // skT token stride (fp32, 128 tok + pad, 528B)
#define TSH2 136            // svT token stride (fp16, 128 tok + pad, 272B)

#define KCH 18              // phase2 K-chunks (K = 576)
#define PK_U32 (NBH * KCH * 1024)   // 589,824 packed B-frag u32
#define PK_HALF (PK_U32 / 2)        // 294,912
#define P2TOK 64            // 1 wave per block

// ---------- OLD (fallback) layout ----------
#define NPAIR2 528
#define NROWS 560
#define BHF (NROWS * 32 + 64)       // 17984
#define SLOT (NBH * BHF)            // 575488
#define TILE 64
#define LSTR 36
#define P1T 320

typedef __attribute__((ext_vector_type(8))) short bf16x8;
typedef __attribute__((ext_vector_type(8))) _Float16 f16x8;
typedef __attribute__((ext_vector_type(4))) _Float16 f16x4;
typedef __attribute__((ext_vector_type(4))) float f32x4;
typedef __attribute__((ext_vector_type(4))) unsigned u32x4;

__device__ __forceinline__ int tri_start(int d) { return (d * (65 - d)) >> 1; }

__device__ __forceinline__ int tri_decode_d(int p) {
    int d = (int)((65.0f - sqrtf((float)(4225 - 8 * p))) * 0.5f);
    if (d < 0) d = 0;
    if (d > 31) d = 31;
    while (d < 31 && tri_start(d + 1) <= p) ++d;
    while (d > 0 && tri_start(d) > p) --d;
    return d;
}

__device__ __forceinline__ void row_operands(int row, int& ia, int& ib) {
    if (row < NPAIR2) {
        const int d = tri_decode_d(row);
        ia = d; ib = d + (row - tri_start(d));
    } else if (row < NROWS) {
        ia = row - NPAIR2; ib = 32;
    } else {
        ia = 34; ib = 34;
    }
}

// fp32[8] -> f16 hi/lo fragments (hi rounding exactly compensated by lo)
__device__ __forceinline__ void split8(const float* p, f16x8& hi, f16x8& lo) {
#pragma unroll
    for (int j = 0; j < 8; ++j) {
        const _Float16 h = (_Float16)p[j];
        hi[j] = h;
        lo[j] = (_Float16)(p[j] - (float)h);
    }
}

#define MF(A, B, C) __builtin_amdgcn_mfma_f32_16x16x32_f16((A), (B), (C), 0, 0, 0)

// =================== Phase 1 (MFMA, fp32-exact A-products) ===================
// W row R = o*32+d (o=0..16, pair (d,(d+o)&31)); R = 544+d: kv1. Sums at SUMOFF1.
// Wave w: offsets {w, w+4, w+8, w+12} + special (w0: o16, w1: kv1, w2: ksum, w3: vsum).
// Staging: two 128-token halves; 4x4 register-tile transpose, all-vector DS writes.
__global__ __launch_bounds__(256) void phase1m_kernel(const float* __restrict__ qkv,
                                                      float* __restrict__ ws) {
    const int chunk = blockIdx.x;
    const int bh = blockIdx.y;
    const int t = threadIdx.x;
    const int w = t >> 6, l = t & 63, g = l >> 4, c16 = l & 15;

    __shared__ float skT[32 * TSF2];       // 16.5 KB
    __shared__ _Float16 svhiT[32 * TSH2];  // 8.5 KB
    __shared__ _Float16 svloT[32 * TSH2];  // 8.5 KB

    const float4* kg4 = (const float4*)(qkv + (size_t)(NBH + bh) * (NTOK * DIM)) + (size_t)chunk * 256 * 8;
    const float4* vg4 = (const float4*)(qkv + (size_t)(2 * NBH + bh) * (NTOK * DIM)) + (size_t)chunk * 256 * 8;

    f32x4 acc[4][2][2];
    f32x4 accS[2][2];
#pragma unroll
    for (int i = 0; i < 4; ++i)
#pragma unroll
        for (int m = 0; m < 2; ++m)
#pragma unroll
            for (int fh = 0; fh < 2; ++fh) acc[i][m][fh] = (f32x4){0.f, 0.f, 0.f, 0.f};
#pragma unroll
    for (int m = 0; m < 2; ++m)
#pragma unroll
        for (int fh = 0; fh < 2; ++fh) accS[m][fh] = (f32x4){0.f, 0.f, 0.f, 0.f};

    const f16x8 ones = {(_Float16)1.f, (_Float16)1.f, (_Float16)1.f, (_Float16)1.f,
                        (_Float16)1.f, (_Float16)1.f, (_Float16)1.f, (_Float16)1.f};

    const int fq = t >> 5;     // 0..7 feature-quad
    const int tq = t & 31;     // 0..31 token-quad (within 128-tok half)

#pragma unroll 1
    for (int half = 0; half < 2; ++half) {
        __syncthreads();
        {   // ---- stage 128 tokens: 4x4 register-tile transpose ----
            const int nb = half * 128;
            float4 kf[4], vf[4];
#pragma unroll
            for (int c = 0; c < 4; ++c) {
                kf[c] = kg4[(size_t)(nb + tq * 4 + c) * 8 + fq];
                vf[c] = vg4[(size_t)(nb + tq * 4 + c) * 8 + fq];
            }
            const float kr[4][4] = {{kf[0].x, kf[1].x, kf[2].x, kf[3].x},
                                    {kf[0].y, kf[1].y, kf[2].y, kf[3].y},
                                    {kf[0].z, kf[1].z, kf[2].z, kf[3].z},
                                    {kf[0].w, kf[1].w, kf[2].w, kf[3].w}};
            const float vr[4][4] = {{vf[0].x, vf[1].x, vf[2].x, vf[3].x},
                                    {vf[0].y, vf[1].y, vf[2].y, vf[3].y},
                                    {vf[0].z, vf[1].z, vf[2].z, vf[3].z},
                                    {vf[0].w, vf[1].w, vf[2].w, vf[3].w}};
#pragma unroll
            for (int r = 0; r < 4; ++r) {
                *(float4*)(skT + (fq * 4 + r) * TSF2 + tq * 4) =
                    (float4){kr[r][0], kr[r][1], kr[r][2], kr[r][3]};
                f16x4 vh, vl;
#pragma unroll
                for (int c = 0; c < 4; ++c) {
                    const _Float16 h = (_Float16)vr[r][c];
                    vh[c] = h;
                    vl[c] = (_Float16)(vr[r][c] - (float)h);
                }
                *(f16x4*)(svhiT + (fq * 4 + r) * TSH2 + tq * 4) = vh;
                *(f16x4*)(svloT + (fq * 4 + r) * TSH2 + tq * 4) = vl;
            }
        }
        __syncthreads();

#pragma unroll 1
        for (int it = 0; it < 4; ++it) {
            const int sl = it * 32 + 8 * g;
            float a0[8], a1[8];
            *(float4*)&a0[0] = *(const float4*)(skT + c16 * TSF2 + sl);
            *(float4*)&a0[4] = *(const float4*)(skT + c16 * TSF2 + sl + 4);
            *(float4*)&a1[0] = *(const float4*)(skT + (16 + c16) * TSF2 + sl);
            *(float4*)&a1[4] = *(const float4*)(skT + (16 + c16) * TSF2 + sl + 4);
            const f16x8 Bh0 = *(const f16x8*)(svhiT + c16 * TSH2 + sl);
            const f16x8 Bh1 = *(const f16x8*)(svhiT + (16 + c16) * TSH2 + sl);
            const f16x8 Bl0 = *(const f16x8*)(svloT + c16 * TSH2 + sl);
            const f16x8 Bl1 = *(const f16x8*)(svloT + (16 + c16) * TSH2 + sl);

#pragma unroll
            for (int i = 0; i < 4; ++i) {
                const int o = w + 4 * i;
                const int r0 = ((c16 + o) & 31) * TSF2;
                const int r1 = ((16 + c16 + o) & 31) * TSF2;
                float e0[8], e1[8], p0[8], p1[8];
                *(float4*)&e0[0] = *(const float4*)(skT + r0 + sl);
                *(float4*)&e0[4] = *(const float4*)(skT + r0 + sl + 4);
                *(float4*)&e1[0] = *(const float4*)(skT + r1 + sl);
                *(float4*)&e1[4] = *(const float4*)(skT + r1 + sl + 4);
#pragma unroll
                for (int j = 0; j < 8; ++j) { p0[j] = a0[j] * e0[j]; p1[j] = a1[j] * e1[j]; }
                f16x8 A0h, A0l, A1h, A1l;
                split8(p0, A0h, A0l);
                split8(p1, A1h, A1l);
                acc[i][0][0] = MF(A0h, Bh0, acc[i][0][0]);
                acc[i][0][0] = MF(A0l, Bh0, acc[i][0][0]);
                acc[i][0][0] = MF(A0h, Bl0, acc[i][0][0]);
                acc[i][0][1] = MF(A0h, Bh1, acc[i][0][1]);
                acc[i][0][1] = MF(A0l, Bh1, acc[i][0][1]);
                acc[i][0][1] = MF(A0h, Bl1, acc[i][0][1]);
                acc[i][1][0] = MF(A1h, Bh0, acc[i][1][0]);
                acc[i][1][0] = MF(A1l, Bh0, acc[i][1][0]);
                acc[i][1][0] = MF(A1h, Bl0, acc[i][1][0]);
                acc[i][1][1] = MF(A1h, Bh1, acc[i][1][1]);
                acc[i][1][1] = MF(A1l, Bh1, acc[i][1][1]);
                acc[i][1][1] = MF(A1h, Bl1, acc[i][1][1]);
            }

            if (w == 0) {            // o=16 (duplicate-symmetric pair rows)
                float p[8];
#pragma unroll
                for (int j = 0; j < 8; ++j) p[j] = a0[j] * a1[j];
                f16x8 Ah, Al;
                split8(p, Ah, Al);
                accS[0][0] = MF(Ah, Bh0, accS[0][0]);
                accS[0][0] = MF(Al, Bh0, accS[0][0]);
                accS[0][0] = MF(Ah, Bl0, accS[0][0]);
                accS[0][1] = MF(Ah, Bh1, accS[0][1]);
                accS[0][1] = MF(Al, Bh1, accS[0][1]);
                accS[0][1] = MF(Ah, Bl1, accS[0][1]);
            } else if (w == 1) {     // kv1: A = k (split)
                f16x8 K0h, K0l, K1h, K1l;
                split8(a0, K0h, K0l);
                split8(a1, K1h, K1l);
                accS[0][0] = MF(K0h, Bh0, accS[0][0]);
                accS[0][0] = MF(K0l, Bh0, accS[0][0]);
                accS[0][0] = MF(K0h, Bl0, accS[0][0]);
                accS[0][1] = MF(K0h, Bh1, accS[0][1]);
                accS[0][1] = MF(K0l, Bh1, accS[0][1]);
                accS[0][1] = MF(K0h, Bl1, accS[0][1]);
                accS[1][0] = MF(K1h, Bh0, accS[1][0]);
                accS[1][0] = MF(K1l, Bh0, accS[1][0]);
                accS[1][0] = MF(K1h, Bl0, accS[1][0]);
                accS[1][1] = MF(K1h, Bh1, accS[1][1]);
                accS[1][1] = MF(K1l, Bh1, accS[1][1]);
                accS[1][1] = MF(K1h, Bl1, accS[1][1]);
            } else if (w == 2) {     // ksum: A = ones, B = k (split)
                f16x8 K0h, K0l, K1h, K1l;
                split8(a0, K0h, K0l);
                split8(a1, K1h, K1l);
                accS[0][0] = MF(ones, K0h, accS[0][0]);
                accS[0][0] = MF(ones, K0l, accS[0][0]);
                accS[1][0] = MF(ones, K1h, accS[1][0]);
                accS[1][0] = MF(ones, K1l, accS[1][0]);
            } else {                 // vsum: A = ones, B = v hi/lo
                accS[0][0] = MF(ones, Bh0, accS[0][0]);
                accS[0][0] = MF(ones, Bl0, accS[0][0]);
                accS[0][1] = MF(ones, Bh1, accS[0][1]);
                accS[0][1] = MF(ones, Bl1, accS[0][1]);
            }
        }
    }

    // ---- store partials to slot (1+chunk) ----
    float* pb = ws + (size_t)SLOT1 * (1 + chunk) + (size_t)bh * BHF1;
#pragma unroll
    for (int i = 0; i < 4; ++i) {
        const int o = w + 4 * i;
#pragma unroll
        for (int m = 0; m < 2; ++m)
#pragma unroll
            for (int fh = 0; fh < 2; ++fh)
#pragma unroll
                for (int r = 0; r < 4; ++r) {
                    const int R = o * 32 + 16 * m + 4 * g + r;
                    pb[(size_t)R * 32 + fh * 16 + c16] = acc[i][m][fh][r];
                }
    }
    if (w == 0) {
#pragma unroll
        for (int fh = 0; fh < 2; ++fh)
#pragma unroll
            for (int r = 0; r < 4; ++r) {
                const int R = 512 + 4 * g + r;
                pb[(size_t)R * 32 + fh * 16 + c16] = accS[0][fh][r];
                pb[(size_t)(R + 16) * 32 + fh * 16 + c16] = accS[0][fh][r];
            }
    } else if (w == 1) {
#pragma unroll
        for (int m = 0; m < 2; ++m)
#pragma unroll
            for (int fh = 0; fh < 2; ++fh)
#pragma unroll
                for (int r = 0; r < 4; ++r) {
                    const int R = 544 + 16 * m + 4 * g + r;
                    pb[(size_t)R * 32 + fh * 16 + c16] = accS[m][fh][r];
                }
    } else if (w == 2) {
        if (g == 0) {
            pb[SUMOFF1 + c16] = accS[0][0][0];
            pb[SUMOFF1 + 16 + c16] = accS[1][0][0];
        }
    } else {
        if (g == 0) {
            pb[SUMOFF1 + 32 + c16] = accS[0][0][0];
            pb[SUMOFF1 + 48 + c16] = accS[0][1][0];
        }
    }
}

// ============ reduce (16 slots) + prep (f16 hi/lo B-frag pack) + sums ============
__global__ __launch_bounds__(256) void reduceprep_kernel(const float* __restrict__ ws,
                                                         float* __restrict__ wsw,
                                                         unsigned* __restrict__ bpk) {
    const int tid = blockIdx.x * 256 + threadIdx.x;
    if (tid < PK_HALF) {
        const int r = tid & 3;
        const int l = (tid >> 2) & 63;
        const int fh = (tid >> 8) & 1;
        const int kcbh = tid >> 9;
        const int kc = kcbh % KCH;
        const int bh = kcbh / KCH;
        const int f = fh * 16 + (l & 15);
        const int k0 = kc * 32 + ((l >> 4) << 3) + 2 * r;
        const float scale = (kc == 0 || kc == 16) ? 0.5f : 1.0f;
        float va = 0.f, vb = 0.f;
        const float* src = ws + (size_t)bh * BHF1 + (size_t)k0 * 32 + f;
#pragma unroll
        for (int c = 1; c <= KCH1; ++c) {
            va += src[(size_t)SLOT1 * c];
            vb += src[(size_t)SLOT1 * c + 32];
        }
        va *= scale; vb *= scale;
        const _Float16 ha = (_Float16)va, hb = (_Float16)vb;
        const _Float16 la = (_Float16)(va - (float)ha), lb = (_Float16)(vb - (float)hb);
        const int widx = ((bh * KCH + kc) * 2 + fh) * 512 + l * 4 + r;
        bpk[widx] = (unsigned)__builtin_bit_cast(unsigned short, ha) |
                    ((unsigned)__builtin_bit_cast(unsigned short, hb) << 16);
        bpk[widx + 256] = (unsigned)__builtin_bit_cast(unsigned short, la) |
                          ((unsigned)__builtin_bit_cast(unsigned short, lb) << 16);
    } else {
        const int tid2 = tid - PK_HALF;
        if (tid2 < NBH * 64) {
            const int bh = tid2 >> 6;
            const int j = tid2 & 63;
            float s = 0.f;
            const float* src = ws + (size_t)bh * BHF1 + SUMOFF1 + j;
#pragma unroll
            for (int c = 1; c <= KCH1; ++c) s += src[(size_t)SLOT1 * c];
            wsw[(size_t)bh * BHF1 + SUMOFF1 + j] = s;
        }
    }
}

// ====== phase 2: y = Phi * W via f16 MFMA (A single, B hi/lo), rolled x4 ======
// 1 wave per block (64 tokens). Chunk kc<17: phi_j = q_j*q_{(j+kc)&31}; kc=17: phi=q.
// qr rotated by 4 per unrolled body (renaming makes intra-body rotations free).
#define EMIT_MFMA(PHIEXPR, KCEXPR) do { \
    unsigned hh[16]; \
    _Pragma("unroll") \
    for (int kp = 0; kp < 16; ++kp) { \
        const int j0 = 2 * kp, j1 = 2 * kp + 1; \
        const float p0 = (PHIEXPR(j0)); \
        const float p1 = (PHIEXPR(j1)); \
        const _Float16 h0 = (_Float16)p0; \
        const _Float16 h1 = (_Float16)p1; \
        hh[kp] = (unsigned)__builtin_bit_cast(unsigned short, h0) | \
                 ((unsigned)__builtin_bit_cast(unsigned short, h1) << 16); \
    } \
    _Pragma("unroll") \
    for (int c4 = 0; c4 < 4; ++c4) { \
        u32x4 vh = {hh[4 * c4], hh[4 * c4 + 1], hh[4 * c4 + 2], hh[4 * c4 + 3]}; \
        *(u32x4*)&sph[t * 20 + c4 * 4] = vh; \
    } \
    const unsigned* bc = bbase + (size_t)(KCEXPR) * 1024; \
    const f16x8 Bh0 = __builtin_bit_cast(f16x8, *(const u32x4*)(bc + 0   + t * 4)); \
    const f16x8 Bl0 = __builtin_bit_cast(f16x8, *(const u32x4*)(bc + 256 + t * 4)); \
    const f16x8 Bh1 = __builtin_bit_cast(f16x8, *(const u32x4*)(bc + 512 + t * 4)); \
    const f16x8 Bl1 = __builtin_bit_cast(f16x8, *(const u32x4*)(bc + 768 + t * 4)); \
    _Pragma("unroll") \
    for (int T = 0; T < 4; ++T) { \
        const int ro = (T * 16 + arow) * 20 + acol; \
        const f16x8 Ah = __builtin_bit_cast(f16x8, *(const u32x4*)&sph[ro]); \
        acc[T][0] = MF(Ah, Bh0, acc[T][0]); \
        acc[T][0] = MF(Ah, Bl0, acc[T][0]); \
        acc[T][1] = MF(Ah, Bh1, acc[T][1]); \
        acc[T][1] = MF(Ah, Bl1, acc[T][1]); \
    } \
} while (0)

__global__ __launch_bounds__(P2TOK) void phase2m_kernel(const float* __restrict__ qkv,
                                                        const float* __restrict__ ws,
                                                        const unsigned* __restrict__ bpk,
                                                        float* __restrict__ out) {
    const int bh = blockIdx.y;
    const int tok0 = blockIdx.x * P2TOK;
    const int t = threadIdx.x;          // 0..63 == lane
    const int arow = t & 15;
    const int acol = (t >> 4) << 2;

    __shared__ unsigned sph[P2TOK * 20];
    __shared__ float sinv[P2TOK];

    float q[32];
    {
        const float4* q4 = (const float4*)(qkv + ((size_t)bh * NTOK + tok0 + t) * DIM);
#pragma unroll
        for (int i = 0; i < 8; ++i) {
            const float4 v = q4[i];
            q[4 * i + 0] = v.x; q[4 * i + 1] = v.y; q[4 * i + 2] = v.z; q[4 * i + 3] = v.w;
        }
    }
    {
        const float* ks = ws + (size_t)bh * BHF1 + SUMOFF1;
        float qk = 0.f;
#pragma unroll
        for (int d = 0; d < 32; ++d) qk += q[d] * ks[d];
        sinv[t] = 1.0f / (0.5f * qk * qk + qk + 1.0f);
    }

    f32x4 acc[4][2];
#pragma unroll
    for (int T = 0; T < 4; ++T)
#pragma unroll
        for (int fh = 0; fh < 2; ++fh) acc[T][fh] = (f32x4){0.f, 0.f, 0.f, 0.f};

    const unsigned* bbase = bpk + (size_t)bh * (KCH * 1024);

    float qr[32];
#pragma unroll
    for (int j = 0; j < 32; ++j) qr[j] = q[j];

#pragma unroll 1
    for (int kc4 = 0; kc4 < 16; kc4 += 4) {
#define PHI_S0(J) (q[(J)] * qr[(J)])
#define PHI_S1(J) (q[(J)] * qr[((J) + 1) & 31])
#define PHI_S2(J) (q[(J)] * qr[((J) + 2) & 31])
#define PHI_S3(J) (q[(J)] * qr[((J) + 3) & 31])
        EMIT_MFMA(PHI_S0, kc4 + 0);
        EMIT_MFMA(PHI_S1, kc4 + 1);
        EMIT_MFMA(PHI_S2, kc4 + 2);
        EMIT_MFMA(PHI_S3, kc4 + 3);
#undef PHI_S0
#undef PHI_S1
#undef PHI_S2
#undef PHI_S3
        // rotate qr by 4
        const float t0 = qr[0], t1 = qr[1], t2 = qr[2], t3 = qr[3];
#pragma unroll
        for (int j = 0; j < 28; ++j) qr[j] = qr[j + 4];
        qr[28] = t0; qr[29] = t1; qr[30] = t2; qr[31] = t3;
    }
    // kc = 16: qr is now q rotated by 16
    {
#define PHI_16(J) (q[(J)] * qr[(J)])
        EMIT_MFMA(PHI_16, 16);
#undef PHI_16
    }
    // kc = 17: kv1, phi = q
    {
#define PHI_Q(J) (q[(J)])
        EMIT_MFMA(PHI_Q, 17);
#undef PHI_Q
    }

    const float* vs = ws + (size_t)bh * BHF1 + SUMOFF1 + 32;
    const float vs0 = vs[t & 15];
    const float vs1 = vs[16 + (t & 15)];
#pragma unroll
    for (int T = 0; T < 4; ++T) {
#pragma unroll
        for (int r = 0; r < 4; ++r) {
            const int row = T * 16 + ((t >> 4) << 2) + r;
            const float iv = sinv[row];
            float* op = out + ((size_t)bh * NTOK + tok0 + row) * DIM + (t & 15);
            op[0]  = (acc[T][0][r] + vs0) * iv;
            op[16] = (acc[T][1][r] + vs1) * iv;
        }
    }
}

// =================== OLD fallback path (proven) ===================
__global__ __launch_bounds__(P1T) void phase1_kernel(const float* __restrict__ qkv,
                                                     float* __restrict__ ws, int direct) {
    const int chunk = blockIdx.x;
    const int bh = blockIdx.y;
    const int CHt = NTOK / gridDim.x;
    const int t = threadIdx.x;
    const float* kptr = qkv + (size_t)(NBH + bh) * (NTOK * DIM);
    const float* vptr = qkv + (size_t)(2 * NBH + bh) * (NTOK * DIM);
    float* base = ws + (direct ? (size_t)0 : (size_t)SLOT * (1 + chunk)) + (size_t)bh * BHF;

    __shared__ __align__(16) float sk[TILE][LSTR];
    __shared__ __align__(16) float sv[TILE][LSTR];

    int ia0, ib0, ia1, ib1;
    row_operands(t, ia0, ib0);
    row_operands(t + P1T, ia1, ib1);
    const float* a0 = &sk[0][ia0];
    const float* b0 = &sk[0][ib0];
    const float* a1 = &sk[0][ia1];
    const float* b1 = &sk[0][ib1];
    const float* sums = (t >= 288) ? &sv[0][t - 288] : ((t >= 256) ? &sk[0][t - 256] : &sk[0][0]);

    float acc0[32], acc1[32];
#pragma unroll
    for (int f = 0; f < 32; ++f) { acc0[f] = 0.f; acc1[f] = 0.f; }
    float accs = 0.f;

    if (t < 64) sk[t][32] = 1.0f;
    else if (t < 128) sk[t - 64][34] = 0.0f;

    const int n0 = chunk * CHt;
    for (int nt = 0; nt < CHt; nt += TILE) {
        __syncthreads();
        if (t < 256) {
            const float4* kg4 = (const float4*)(kptr + (size_t)(n0 + nt) * DIM);
            const float4* vg4 = (const float4*)(vptr + (size_t)(n0 + nt) * DIM);
            const int i0 = t, i1 = t + 256;
            *(float4*)&sk[i0 >> 3][(i0 & 7) << 2] = kg4[i0];
            *(float4*)&sk[i1 >> 3][(i1 & 7) << 2] = kg4[i1];
            *(float4*)&sv[i0 >> 3][(i0 & 7) << 2] = vg4[i0];
            *(float4*)&sv[i1 >> 3][(i1 & 7) << 2] = vg4[i1];
        }
        __syncthreads();
#pragma unroll 2
        for (int nn = 0; nn < TILE; ++nn) {
            const float s0 = a0[nn * LSTR] * b0[nn * LSTR];
            const float s1 = a1[nn * LSTR] * b1[nn * LSTR];
            const float* vrow = vptr + (size_t)(n0 + nt + nn) * DIM;
            float4 w[8];
#pragma unroll
            for (int j = 0; j < 8; ++j) w[j] = ((const float4*)vrow)[j];
#pragma unroll
            for (int j = 0; j < 8; ++j) {
                acc0[4 * j + 0] += s0 * w[j].x; acc0[4 * j + 1] += s0 * w[j].y;
                acc0[4 * j + 2] += s0 * w[j].z; acc0[4 * j + 3] += s0 * w[j].w;
                acc1[4 * j + 0] += s1 * w[j].x; acc1[4 * j + 1] += s1 * w[j].y;
                acc1[4 * j + 2] += s1 * w[j].z; acc1[4 * j + 3] += s1 * w[j].w;
            }
            if (t >= 256) accs += sums[nn * LSTR];
        }
    }

    {
        float* dst = base + (size_t)t * 32;
#pragma unroll
        for (int j = 0; j < 8; ++j) {
            float4 v; v.x = acc0[4 * j]; v.y = acc0[4 * j + 1];
            v.z = acc0[4 * j + 2]; v.w = acc0[4 * j + 3];
            ((float4*)dst)[j] = v;
        }
    }
    if (t < 240) {
        float* dst = base + (size_t)(t + P1T) * 32;
#pragma unroll
        for (int j = 0; j < 8; ++j) {
            float4 v; v.x = acc1[4 * j]; v.y = acc1[4 * j + 1];
            v.z = acc1[4 * j + 2]; v.w = acc1[4 * j + 3];
            ((float4*)dst)[j] = v;
        }
    }
    if (t >= 256) base[NROWS * 32 + (t - 256)] = accs;
}

__global__ __launch_bounds__(256) void phase2_kernel(const float* __restrict__ qkv,
                                                     const float* __restrict__ ws,
                                                     float* __restrict__ out) {
    const int bh = blockIdx.y;
    const int f0 = blockIdx.z << 4;
    const int t = threadIdx.x;
    const int tok0 = blockIdx.x * 256;
    const float* qptr = qkv + (size_t)bh * (NTOK * DIM) + (size_t)tok0 * DIM;
    const float* base = ws + (size_t)bh * BHF;
    const float* ksum = base + NROWS * 32;
    const float* vsum = ksum + 32;

    __shared__ float qT[32][256];
    {
        const float4* q4 = (const float4*)qptr + (size_t)t * 8;
#pragma unroll
        for (int i = 0; i < 8; ++i) {
            const float4 v = q4[i];
            qT[4 * i + 0][t] = v.x; qT[4 * i + 1][t] = v.y;
            qT[4 * i + 2][t] = v.z; qT[4 * i + 3][t] = v.w;
        }
    }
    __syncthreads();

    float y[16];
#pragma unroll
    for (int j = 0; j < 4; ++j) {
        const float4 v = *(const float4*)(vsum + f0 + 4 * j);
        y[4 * j + 0] = v.x; y[4 * j + 1] = v.y; y[4 * j + 2] = v.z; y[4 * j + 3] = v.w;
    }
    float qk = 0.f;
    const float* rowp = base + f0;
#pragma unroll 1
    for (int d = 0; d < 32; ++d) {
        const float qd = qT[d][t];
        qk += qd * ksum[d];
        {
            const float s = 0.5f * qd * qd;
            const float4* r = (const float4*)rowp;
#pragma unroll
            for (int j = 0; j < 4; ++j) {
                const float4 w = r[j];
                y[4 * j + 0] += s * w.x; y[4 * j + 1] += s * w.y;
                y[4 * j + 2] += s * w.z; y[4 * j + 3] += s * w.w;
            }
            rowp += 32;
        }
#pragma unroll 4
        for (int e = d + 1; e < 32; ++e) {
            const float s = qd * qT[e][t];
            const float4* r = (const float4*)rowp;
#pragma unroll
            for (int j = 0; j < 4; ++j) {
                const float4 w = r[j];
                y[4 * j + 0] += s * w.x; y[4 * j + 1] += s * w.y;
                y[4 * j + 2] += s * w.z; y[4 * j + 3] += s * w.w;
            }
            rowp += 32;
        }
    }
#pragma unroll 4
    for (int d = 0; d < 32; ++d) {
        const float qd = qT[d][t];
        const float4* r = (const float4*)rowp;
#pragma unroll
        for (int j = 0; j < 4; ++j) {
            const float4 w = r[j];
            y[4 * j + 0] += qd * w.x; y[4 * j + 1] += qd * w.y;
            y[4 * j + 2] += qd * w.z; y[4 * j + 3] += qd * w.w;
        }
        rowp += 32;
    }
    const float inv = 1.0f / (0.5f * qk * qk + qk + 1.0f);
    float4* o4 = (float4*)(out + (size_t)bh * (NTOK * DIM) + (size_t)(tok0 + t) * DIM + f0);
#pragma unroll
    for (int j = 0; j < 4; ++j) {
        float4 v;
        v.x = y[4 * j + 0] * inv; v.y = y[4 * j + 1] * inv;
        v.z = y[4 * j + 2] * inv; v.w = y[4 * j + 3] * inv;
        o4[j] = v;
    }
}

extern "C" void kernel_launch(void* const* d_in, const int* in_sizes, int n_in,
                              void* d_out, int out_size, void* d_ws, size_t ws_size,
                              hipStream_t stream) {
    const float* qkv = (const float*)d_in[0];
    float* out = (float*)d_out;
    float* ws = (float*)d_ws;

    const size_t need = ((size_t)(1 + KCH1) * SLOT1 + PK_U32) * 4;
    if (ws_size >= need) {
        unsigned* bpk = (unsigned*)(ws + (size_t)(1 + KCH1) * SLOT1);
        phase1m_kernel<<<dim3(KCH1, NBH), dim3(256), 0, stream>>>(qkv, ws);
        reduceprep_kernel<<<dim3((PK_HALF + NBH * 64) / 256), dim3(256), 0, stream>>>(ws, ws, bpk);
        phase2m_kernel<<<dim3(NTOK / P2TOK, NBH), dim3(P2TOK), 0, stream>>>(qkv, ws, bpk, out);
    } else {
        phase1_kernel<<<dim3(1, NBH), dim3(P1T), 0, stream>>>(qkv, ws, 1);
        phase2_kernel<<<dim3(NTOK / 256, NBH, 2), dim3(256), 0, stream>>>(qkv, ws, out);
    }
}